// Round 15
// baseline (1052.531 us; speedup 1.0000x reference)
//
#include <hip/hip_runtime.h>

typedef unsigned short u16;
typedef unsigned int u32;
using bf16x8 = __attribute__((ext_vector_type(8))) short;
using f32x4  = __attribute__((ext_vector_type(4))) float;

#define EPS 1e-5f

__device__ __forceinline__ u16 f2bf(float f) {
    union { float f; u32 u; } v; v.f = f;
    u32 r = v.u + 0x7FFFu + ((v.u >> 16) & 1u);   // RNE
    return (u16)(r >> 16);
}
__device__ __forceinline__ float bf2f(u16 u) {
    union { u32 u; float f; } v; v.u = ((u32)u) << 16;
    return v.f;
}
__device__ __forceinline__ u32 pack2(float a, float b) {
    return (u32)f2bf(a) | ((u32)f2bf(b) << 16);
}
__device__ __forceinline__ void gl16(const void* g, void* s) {
    __builtin_amdgcn_global_load_lds(
        (const __attribute__((address_space(1))) u32*)g,
        (__attribute__((address_space(3))) u32*)s, 16, 0, 0);
}
__device__ __forceinline__ float sigm(float x) { return 1.f / (1.f + __expf(-x)); }

// ---------------- fp32 -> bf16 convert ----------------
__global__ void conv_bf16(const float* __restrict__ src, u16* __restrict__ dst, int n4) {
    int i = blockIdx.x * 256 + threadIdx.x;
    if (i >= n4) return;
    float4 v = reinterpret_cast<const float4*>(src)[i];
    u32 lo = (u32)f2bf(v.x) | ((u32)f2bf(v.y) << 16);
    u32 hi = (u32)f2bf(v.z) | ((u32)f2bf(v.w) << 16);
    reinterpret_cast<uint2*>(dst)[i] = make_uint2(lo, hi);
}

__global__ void conv3_bf16(const float* __restrict__ s0, const float* __restrict__ s1,
                           const float* __restrict__ s2, u16* __restrict__ d0,
                           u16* __restrict__ d1, u16* __restrict__ d2, int n4) {
    int i = blockIdx.x * 256 + threadIdx.x;
    if (i >= n4) return;
    const float* src = (blockIdx.y == 0) ? s0 : (blockIdx.y == 1) ? s1 : s2;
    u16* dst = (blockIdx.y == 0) ? d0 : (blockIdx.y == 1) ? d1 : d2;
    float4 v = reinterpret_cast<const float4*>(src)[i];
    u32 lo = (u32)f2bf(v.x) | ((u32)f2bf(v.y) << 16);
    u32 hi = (u32)f2bf(v.z) | ((u32)f2bf(v.w) << 16);
    reinterpret_cast<uint2*>(dst)[i] = make_uint2(lo, hi);
}

// ---------------- RMSNorm: fp32 [4096,2048] -> bf16 ----------------
__global__ void rmsnorm_k(const float* __restrict__ x, const float* __restrict__ wt,
                          u16* __restrict__ out) {
    __shared__ float red[4];
    const int row = blockIdx.x, t = threadIdx.x;
    const float* xr = x + (size_t)row * 2048;
    float4 v0 = *reinterpret_cast<const float4*>(&xr[t * 8]);
    float4 v1 = *reinterpret_cast<const float4*>(&xr[t * 8 + 4]);
    float ss = v0.x*v0.x + v0.y*v0.y + v0.z*v0.z + v0.w*v0.w
             + v1.x*v1.x + v1.y*v1.y + v1.z*v1.z + v1.w*v1.w;
#pragma unroll
    for (int d = 1; d < 64; d <<= 1) ss += __shfl_xor(ss, d);
    if ((t & 63) == 0) red[t >> 6] = ss;
    __syncthreads();
    const float tot = red[0] + red[1] + red[2] + red[3];
    const float s = 1.f / sqrtf(tot * (1.f / 2048.f) + EPS);
    float4 w0 = *reinterpret_cast<const float4*>(&wt[t * 8]);
    float4 w1 = *reinterpret_cast<const float4*>(&wt[t * 8 + 4]);
    u32 o[4];
    o[0] = pack2(v0.x * s * w0.x, v0.y * s * w0.y);
    o[1] = pack2(v0.z * s * w0.z, v0.w * s * w0.w);
    o[2] = pack2(v1.x * s * w1.x, v1.y * s * w1.y);
    o[3] = pack2(v1.z * s * w1.z, v1.w * s * w1.w);
    *reinterpret_cast<uint4*>(&out[(size_t)row * 2048 + t * 8]) =
        make_uint4(o[0], o[1], o[2], o[3]);
}

// ---------------- L2 norm of q/k rows (in place); q scaled by temp[h] ----------------
__global__ void qk_l2norm(u16* __restrict__ qkv, const float* __restrict__ temp) {
    const int wid = blockIdx.x * 4 + (threadIdx.x >> 6);
    const int l = threadIdx.x & 63;
    const int n = wid >> 5;
    const int rem = wid & 31;
    const int which = rem >> 4;
    const int h = rem & 15;
    u16* p = qkv + (size_t)n * 6144 + which * 2048 + h * 128 + l * 2;
    u32 v = *reinterpret_cast<const u32*>(p);
    float f0 = bf2f((u16)(v & 0xffff)), f1 = bf2f((u16)(v >> 16));
    float ss = f0 * f0 + f1 * f1;
#pragma unroll
    for (int d = 1; d < 64; d <<= 1) ss += __shfl_xor(ss, d);
    float sc = 1.f / fmaxf(sqrtf(ss), 1e-12f);
    if (which == 0) sc *= temp[h];
    *reinterpret_cast<u32*>(p) = pack2(f0 * sc, f1 * sc);
}

// ================= FFN fused GEMM+SwiGLU, m201 8-phase counted-vmcnt schedule ==============
// 256x256 tile, waves 2Mx4N (per-wave 128x64), LDS 2 buf x {A0,A1,B0,B1} 16KB slots.
// Slot lifetimes: B slots dead after p0 (frags->regs); A slots live through p3.
// Stagger: tile T stages A0(T+1)@p0, A1(T+1)@p1 (other buf), B0(T+2)@p2, B1(T+2)@p3
// (current buf's freed B slots). One vmcnt(4) per tile boundary drains B(T+1)+A(T+1)
// (issued >=3 phases prior); B(T+2) stays in flight. Invariant entering T: 4 outstanding.
__global__ __launch_bounds__(512, 1)
void gemm_swiglu(const u16* __restrict__ A, const u16* __restrict__ W0,
                 const u16* __restrict__ W1, u16* __restrict__ combo, int K) {
    extern __shared__ u16 lds[];   // 2 x 32768 u16 = 128 KB
    const int orig = blockIdx.x;
    const int xcd = orig & 7, lin = orig >> 3;
    const int wgid = xcd * 32 + lin;
    const int qsel = wgid & 1;
    const int tix = wgid >> 1;
    const int g = tix >> 5;
    const int rem = tix & 31;
    const int bn = rem >> 2;
    const int bm = (g << 2) + (rem & 3);
    const u16* B = qsel ? W1 : W0;

    const int t = threadIdx.x;
    const int w = t >> 6, l = t & 63;
    const int wr = w >> 2, wc = w & 3;
    const int lr = l & 15, lg = l >> 4;
    const int NT = K >> 6;

    const int srow = t >> 3;
    const int scg  = (t & 7) ^ (srow & 7);
    const u16* aS0 = A + (size_t)(bm * 256 + srow) * K + scg * 8;
    const u16* aS1 = aS0 + (size_t)128 * K;
    const size_t r64 = (size_t)64 * K;

#define STG(slot, src, ko) do {                                     \
        gl16((src) + (ko), (slot) + t * 8);                         \
        gl16((src) + (ko) + r64, (slot) + 4096 + t * 8);            \
    } while (0)

    const int xr = (lr & 7) << 4;
    const int kof[2] = { ((lg) << 4) ^ xr, ((4 + lg) << 4) ^ xr };

    f32x4 acc[8][4];
    u32 pk[8][4][2];

    for (int pan = 0; pan < 3; ++pan) {
        const u16* bS0 = B + (size_t)(pan * 2048 + bn * 256 + srow) * K + scg * 8;
        const u16* bS1 = bS0 + (size_t)128 * K;
        // prologue: tile0 {A0,A1,B0,B1} -> buf0; B0,B1(tile1) -> buf1 (12 loads)
        STG(lds + 0,     aS0, 0);
        STG(lds + 8192,  aS1, 0);
        STG(lds + 16384, bS0, 0);
        STG(lds + 24576, bS1, 0);
        if (NT > 1) {
            STG(lds + 32768 + 16384, bS0, 64);
            STG(lds + 32768 + 24576, bS1, 64);
        }
        // combine previous panel's acc while loads fly (VALU only)
        if (pan == 1) {
#pragma unroll
            for (int m = 0; m < 8; m++)
#pragma unroll
                for (int n = 0; n < 4; n++)
#pragma unroll
                    for (int h = 0; h < 2; h++) {
                        const float a0 = acc[m][n][2 * h], a1 = acc[m][n][2 * h + 1];
                        pk[m][n][h] = pack2(a0 * sigm(a0), a1 * sigm(a1));
                    }
        } else if (pan == 2) {
#pragma unroll
            for (int m = 0; m < 8; m++)
#pragma unroll
                for (int n = 0; n < 4; n++)
#pragma unroll
                    for (int h = 0; h < 2; h++) {
                        const u32 sv = pk[m][n][h];
                        const float t0 = bf2f((u16)(sv & 0xffff)) * acc[m][n][2 * h];
                        const float t1 = bf2f((u16)(sv >> 16)) * acc[m][n][2 * h + 1];
                        pk[m][n][h] = pack2(t0, t1);
                    }
        }
        if (NT > 1) asm volatile("s_waitcnt vmcnt(4)" ::: "memory");  // tile0 resident; B(1) flying
        else        asm volatile("s_waitcnt vmcnt(0)" ::: "memory");
        __builtin_amdgcn_s_barrier();

#pragma unroll
        for (int i = 0; i < 8; i++)
#pragma unroll
            for (int j = 0; j < 4; j++) acc[i][j] = (f32x4){0.f, 0.f, 0.f, 0.f};

        for (int T = 0; T < NT; ++T) {
            const char* base = (const char*)lds + (size_t)(T & 1) * 65536;
            u16* nb = lds + (size_t)((T + 1) & 1) * 32768;   // next buf (A dest)
            u16* cb = lds + (size_t)(T & 1) * 32768;         // current buf (B dest for T+2)
            const bool s1 = (T + 1) < NT, s2 = (T + 2) < NT;
            const size_t ko1 = (size_t)(T + 1) * 64;
            const size_t ko2 = (size_t)(T + 2) * 64;
            const char* aB = base + wr * 16384;
            const char* bB = base + 32768 + (wc >> 1) * 16384 + (wc & 1) * 8192;
            bf16x8 bfr[4][2];
#pragma unroll
            for (int p = 0; p < 4; ++p) {
                const int ks = p >> 1, mh = p & 1;
                bf16x8 af[4];
#pragma unroll
                for (int m2 = 0; m2 < 4; m2++) {
                    const int ra = mh * 64 + m2 * 16 + lr;
                    af[m2] = *reinterpret_cast<const bf16x8*>(aB + ra * 128 + kof[ks]);
                }
                if (p == 0) {
#pragma unroll
                    for (int n = 0; n < 4; n++) {
                        const int rb = n * 16 + lr;
                        bfr[n][0] = *reinterpret_cast<const bf16x8*>(bB + rb * 128 + kof[0]);
                        bfr[n][1] = *reinterpret_cast<const bf16x8*>(bB + rb * 128 + kof[1]);
                    }
                }
                // staggered staging: A(T+1) early (other buf), B(T+2) late (freed B slots)
                if (p == 0 && s1) STG(nb + 0,     aS0, ko1);
                if (p == 1 && s1) STG(nb + 8192,  aS1, ko1);
                if (p == 2 && s2) STG(cb + 16384, bS0, ko2);
                if (p == 3 && s2) STG(cb + 24576, bS1, ko2);
                __builtin_amdgcn_s_barrier();
                __builtin_amdgcn_s_setprio(1);
#pragma unroll
                for (int m2 = 0; m2 < 4; m2++)
#pragma unroll
                    for (int n = 0; n < 4; n++)
                        acc[mh * 4 + m2][n] = __builtin_amdgcn_mfma_f32_16x16x32_bf16(
                            af[m2], bfr[n][ks], acc[mh * 4 + m2][n], 0, 0, 0);
                __builtin_amdgcn_s_setprio(0);
                if (p == 3) {
                    if (s2)      asm volatile("s_waitcnt vmcnt(4)" ::: "memory"); // drains B(T+1),A(T+1)
                    else if (s1) asm volatile("s_waitcnt vmcnt(0)" ::: "memory"); // epilogue
                }
                __builtin_amdgcn_s_barrier();
            }
        }
    }
#undef STG

    const int cbase = qsel * 2048 + bn * 256;
#pragma unroll
    for (int m = 0; m < 8; m++) {
        const int row = bm * 256 + wr * 128 + m * 16 + lg * 4;
#pragma unroll
        for (int n = 0; n < 4; n++) {
            const int col = cbase + wc * 64 + n * 16 + lr;
#pragma unroll
            for (int h = 0; h < 2; h++) {
                const u32 tv = pk[m][n][h];
                const float o0 = bf2f((u16)(tv & 0xffff)) * sigm(acc[m][n][2 * h]);
                const float o1 = bf2f((u16)(tv >> 16)) * sigm(acc[m][n][2 * h + 1]);
                combo[(size_t)(row + 2 * h) * 8192 + col] = f2bf(o0);
                combo[(size_t)(row + 2 * h + 1) * 8192 + col] = f2bf(o1);
            }
        }
    }
}

// ================= unified NT GEMM: 128x256, BK=64, 1 barrier per K-tile =================
template <int EPI>
__global__ __launch_bounds__(512, 1)
void gemm_u(const u16* __restrict__ A, const u16* __restrict__ B,
            float* __restrict__ outF, u16* __restrict__ outB,
            const float* __restrict__ bias, const float* __restrict__ addend,
            const float* __restrict__ resid, float* __restrict__ outG,
            int M, int N, int K, int ldc) {
    extern __shared__ u16 lds[];   // 2 bufs x 24576 u16 = 98304 B
    const int nbn = N >> 8;
    const int nwg = (M >> 7) * nbn;
    const int orig = blockIdx.x;
    const int q8 = nwg >> 3, r8 = nwg & 7;
    const int xcd = orig & 7, lin = orig >> 3;
    const int wgid = (xcd < r8 ? xcd * (q8 + 1) : r8 * (q8 + 1) + (xcd - r8) * q8) + lin;
    const int g = wgid / (nbn << 3);
    const int rem = wgid - g * (nbn << 3);
    const int bn = rem >> 3;
    const int bm = (g << 3) + (rem & 7);

    const int t = threadIdx.x;
    const int w = t >> 6, l = t & 63;
    const int wr = w >> 2, wc = w & 3;
    const int lr = l & 15, lg = l >> 4;
    const int NT = K >> 6;

    const int pr = t >> 3, ps = t & 7;
    const int sg = ps ^ (pr & 7);
    const u16* aSrc = A + (size_t)(bm * 128 + pr) * K + sg * 8;
    const u16* bSrc = B + (size_t)(bn * 256 + pr) * K + sg * 8;
    const size_t rowStep = (size_t)64 * K;

#define STG_A(bi, ko) do { u16* da = lds + (bi) * 24576 + t * 8;                 \
        gl16(aSrc + (ko), da); gl16(aSrc + rowStep + (ko), da + 4096); } while (0)
#define STG_B01(bi, ko) do { u16* db = lds + (bi) * 24576 + 8192 + t * 8;        \
        gl16(bSrc + (ko), db); gl16(bSrc + rowStep + (ko), db + 4096); } while (0)
#define STG_B23(bi, ko) do { u16* db = lds + (bi) * 24576 + 8192 + t * 8;        \
        gl16(bSrc + 2 * rowStep + (ko), db + 8192);                              \
        gl16(bSrc + 3 * rowStep + (ko), db + 12288); } while (0)

    f32x4 acc[4][4];
#pragma unroll
    for (int i = 0; i < 4; i++)
#pragma unroll
        for (int j = 0; j < 4; j++) acc[i][j] = (f32x4){0.f, 0.f, 0.f, 0.f};

    const int xr = (lr & 7) << 4;
    const int kof[2] = { ((lg) << 4) ^ xr, ((4 + lg) << 4) ^ xr };

    STG_A(0, 0); STG_B01(0, 0); STG_B23(0, 0);
    asm volatile("s_waitcnt vmcnt(0)" ::: "memory");
    __builtin_amdgcn_s_barrier();

    for (int T = 0; T < NT; ++T) {
        const char* bufA = (const char*)lds + (size_t)(T & 1) * 49152;
        const char* bufB = bufA + 16384;
        const int sbi = (T + 1) & 1;
        const bool st = (T + 1) < NT;
        const size_t ko = (size_t)(T + 1) * 64;
        bf16x8 bf[4][2];
#pragma unroll
        for (int n = 0; n < 4; n++) {
            const int rb = wc * 64 + n * 16 + lr;
            bf[n][0] = *reinterpret_cast<const bf16x8*>(bufB + rb * 128 + kof[0]);
            bf[n][1] = *reinterpret_cast<const bf16x8*>(bufB + rb * 128 + kof[1]);
        }
#pragma unroll
        for (int p = 0; p < 4; ++p) {
            const int ks = p >> 1, mh = p & 1;
            bf16x8 af[2];
#pragma unroll
            for (int m2 = 0; m2 < 2; m2++) {
                const int ra = wr * 64 + (mh * 2 + m2) * 16 + lr;
                af[m2] = *reinterpret_cast<const bf16x8*>(bufA + ra * 128 + kof[ks]);
            }
            if (st) {
                if (p == 0) STG_A(sbi, ko);
                if (p == 1) STG_B01(sbi, ko);
                if (p == 2) STG_B23(sbi, ko);
            }
            __builtin_amdgcn_s_setprio(1);
#pragma unroll
            for (int m2 = 0; m2 < 2; m2++)
#pragma unroll
                for (int n = 0; n < 4; n++)
                    acc[mh * 2 + m2][n] = __builtin_amdgcn_mfma_f32_16x16x32_bf16(
                        af[m2], bf[n][ks], acc[mh * 2 + m2][n], 0, 0, 0);
            __builtin_amdgcn_s_setprio(0);
        }
        if (st) {
            asm volatile("s_waitcnt vmcnt(0)" ::: "memory");
            __builtin_amdgcn_s_barrier();
        }
    }
#undef STG_A
#undef STG_B01
#undef STG_B23

#pragma unroll
    for (int m = 0; m < 4; m++) {
        const int row = bm * 128 + wr * 64 + m * 16 + lg * 4;
#pragma unroll
        for (int n = 0; n < 4; n++) {
            const int col = bn * 256 + wc * 64 + n * 16 + lr;
#pragma unroll
            for (int q = 0; q < 4; q++) {
                const size_t idx = (size_t)(row + q) * ldc + col;
                const float v = acc[m][n][q];
                if (EPI == 0) {
                    outB[idx] = f2bf(v);
                } else if (EPI == 1) {
                    outF[idx] = v;
                    outB[idx] = f2bf(v);
                } else {
                    const float g2 = sigm(v + bias[col]);
                    outG[idx] = g2 * addend[idx] + (1.f - g2) * resid[idx];
                }
            }
        }
    }
}

// ---------------- causal flash attention (QBLK=128, 8 waves, reg-staged dbuf) ----------------
#define VSWZ(dh) (((((dh) >> 3) ^ (dh)) & 7) << 4)
__global__ __launch_bounds__(512) void flash_attn(const u16* __restrict__ qkv,
                                                  u16* __restrict__ out) {
    __shared__ u16 klds[2][64 * 128];
    __shared__ u16 vlds[2][128 * 64];
    __shared__ u16 plds[8][16 * 64];
    const int t = threadIdx.x, w = t >> 6, l = t & 63;
    const int lr = l & 15, lg = l >> 4;
    const int b0 = blockIdx.x;
    const int xcd = b0 & 7, i0 = b0 >> 3;
    const int bh = ((i0 & 3) << 3) | xcd;
    const int p = i0 >> 2;
    const int b = bh >> 4, h = bh & 15;
    const size_t base = (size_t)b * 2048;
    const int sr0 = t >> 4;
    const int sc0 = (t & 15) << 3;

    uint4 kreg0, kreg1, vreg0, vreg1;

#define STAGE_LOAD(KT) do {                                                          \
        const size_t gg = (base + (size_t)(KT) * 64 + sr0) * 6144 + h * 128 + sc0;   \
        kreg0 = *reinterpret_cast<const uint4*>(&qkv[gg + 2048]);                    \
        vreg0 = *reinterpret_cast<const uint4*>(&qkv[gg + 4096]);                    \
        kreg1 = *reinterpret_cast<const uint4*>(&qkv[gg + 32 * 6144 + 2048]);        \
        vreg1 = *reinterpret_cast<const uint4*>(&qkv[gg + 32 * 6144 + 4096]);        \
    } while (0)

#define STAGE_WRITE(BUF) do {                                                                     \
        char* kb = (char*)&klds[BUF][0];                                                          \
        char* vb = (char*)&vlds[BUF][0];                                                          \
        *reinterpret_cast<uint4*>(kb + ((sr0 * 256 + sc0 * 2) ^ ((sr0 & 7) << 4))) = kreg0;       \
        *reinterpret_cast<uint4*>(kb + (((sr0 + 32) * 256 + sc0 * 2) ^ ((sr0 & 7) << 4))) = kreg1;\
        union { uint4 u; u16 s[8]; } vv;                                                          \
        vv.u = vreg0;                                                                             \
        _Pragma("unroll")                                                                         \
        for (int jj = 0; jj < 8; jj++) {                                                          \
            const int dh = sc0 + jj;                                                              \
            *reinterpret_cast<u16*>(vb + ((dh * 128 + sr0 * 2) ^ VSWZ(dh))) = vv.s[jj];           \
        }                                                                                         \
        vv.u = vreg1;                                                                             \
        _Pragma("unroll")                                                                         \
        for (int jj = 0; jj < 8; jj++) {                                                          \
            const int dh = sc0 + jj;                                                              \
            *reinterpret_cast<u16*>(vb + ((dh * 128 + (sr0 + 32) * 2) ^ VSWZ(dh))) = vv.s[jj];    \
        }                                                                                         \
    } while (0)

    for (int phase = 0; phase < 2; ++phase) {
        const int qt = phase ? (15 - p) : p;
        const int last = 2 * qt + 1;
        const int qrow = qt * 128 + w * 16 + lr;
        const int qr0 = qt * 128 + w * 16 + lg * 4;
        bf16x8 qf[4];
#pragma unroll
        for (int kk = 0; kk < 4; kk++)
            qf[kk] = *reinterpret_cast<const bf16x8*>(
                &qkv[(base + qrow) * 6144 + h * 128 + kk * 32 + lg * 8]);
        f32x4 o[8];
#pragma unroll
        for (int i = 0; i < 8; i++) o[i] = (f32x4){0.f, 0.f, 0.f, 0.f};
        float m[4] = {-1e30f, -1e30f, -1e30f, -1e30f};
        float ls[4] = {0.f, 0.f, 0.f, 0.f};

        STAGE_LOAD(0);
        int cur = 0;
        STAGE_WRITE(0);
        __syncthreads();

        for (int kt = 0; kt <= last; ++kt) {
            if (kt < last) STAGE_LOAD(kt + 1);
            const char* kb = (const char*)&klds[cur][0];
            const char* vb = (const char*)&vlds[cur][0];
            f32x4 s[4];
#pragma unroll
            for (int nf = 0; nf < 4; nf++) {
                f32x4 a = (f32x4){0.f, 0.f, 0.f, 0.f};
                const int kv = nf * 16 + lr;
#pragma unroll
                for (int kk = 0; kk < 4; kk++) {
                    bf16x8 kf = *reinterpret_cast<const bf16x8*>(
                        kb + ((kv * 256 + kk * 64 + lg * 16) ^ ((kv & 7) << 4)));
                    a = __builtin_amdgcn_mfma_f32_16x16x32_bf16(qf[kk], kf, a, 0, 0, 0);
                }
                s[nf] = a;
            }
            if (kt >= 2 * qt) {
#pragma unroll
                for (int nf = 0; nf < 4; nf++) {
                    const int kvi = kt * 64 + nf * 16 + lr;
#pragma unroll
                    for (int q = 0; q < 4; q++)
                        if (kvi > qr0 + q) s[nf][q] = -1e30f;
                }
            }
            float mx[4] = {-1e30f, -1e30f, -1e30f, -1e30f};
#pragma unroll
            for (int nf = 0; nf < 4; nf++)
#pragma unroll
                for (int q = 0; q < 4; q++) mx[q] = fmaxf(mx[q], s[nf][q]);
#pragma unroll
            for (int q = 0; q < 4; q++) {
#pragma unroll
                for (int d = 1; d < 16; d <<= 1) mx[q] = fmaxf(mx[q], __shfl_xor(mx[q], d));
            }
            float fac[4], rs[4];
#pragma unroll
            for (int q = 0; q < 4; q++) {
                const float mn = fmaxf(m[q], mx[q]);
                fac[q] = __expf(m[q] - mn);
                m[q] = mn;
                rs[q] = 0.f;
            }
#pragma unroll
            for (int nf = 0; nf < 4; nf++) {
#pragma unroll
                for (int q = 0; q < 4; q++) {
                    const float pv = __expf(s[nf][q] - m[q]);
                    s[nf][q] = pv;
                    rs[q] += pv;
                }
            }
#pragma unroll
            for (int nf = 0; nf < 4; nf++) {
                const int col = nf * 16 + lr;
#pragma unroll
                for (int q = 0; q < 4; q++) {
                    const int row = lg * 4 + q;
                    *reinterpret_cast<u16*>((char*)&plds[w][0] +
                        ((row * 128 + col * 2) ^ ((row & 7) << 4))) = f2bf(s[nf][q]);
                }
            }
#pragma unroll
            for (int q = 0; q < 4; q++) {
#pragma unroll
                for (int d = 1; d < 16; d <<= 1) rs[q] += __shfl_xor(rs[q], d);
                ls[q] = ls[q] * fac[q] + rs[q];
            }
#pragma unroll
            for (int nf2 = 0; nf2 < 8; nf2++)
#pragma unroll
                for (int q = 0; q < 4; q++) o[nf2][q] *= fac[q];
#pragma unroll
            for (int ks = 0; ks < 2; ks++) {
                bf16x8 pf = *reinterpret_cast<const bf16x8*>((char*)&plds[w][0] +
                    ((lr * 128 + ks * 64 + lg * 16) ^ ((lr & 7) << 4)));
#pragma unroll
                for (int nf2 = 0; nf2 < 8; nf2++) {
                    const int dh = nf2 * 16 + lr;
                    bf16x8 vf = *reinterpret_cast<const bf16x8*>(
                        vb + ((dh * 128 + ks * 64 + lg * 16) ^ VSWZ(dh)));
                    o[nf2] = __builtin_amdgcn_mfma_f32_16x16x32_bf16(pf, vf, o[nf2], 0, 0, 0);
                }
            }
            if (kt < last) STAGE_WRITE(cur ^ 1);
            __syncthreads();
            cur ^= 1;
        }
#pragma unroll
        for (int nf2 = 0; nf2 < 8; nf2++) {
            const int col = h * 128 + nf2 * 16 + lr;
#pragma unroll
            for (int q = 0; q < 4; q++) {
                const float v = o[nf2][q] / ls[q];
                out[(base + qr0 + q) * 2048 + col] = f2bf(v);
            }
        }
        __syncthreads();
    }
#undef STAGE_LOAD
#undef STAGE_WRITE
}

// ---------------- launch ----------------
extern "C" void kernel_launch(void* const* d_in, const int* in_sizes, int n_in,
                              void* d_out, int out_size, void* d_ws, size_t ws_size,
                              hipStream_t stream) {
    const float* x      = (const float*)d_in[0];
    const float* q_w    = (const float*)d_in[1];
    const float* k_w    = (const float*)d_in[2];
    const float* v_w    = (const float*)d_in[3];
    const float* o_w    = (const float*)d_in[4];
    const float* temp   = (const float*)d_in[5];
    const float* ln1_w  = (const float*)d_in[6];
    const float* ln2_w  = (const float*)d_in[7];
    const float* gate_w = (const float*)d_in[8];
    const float* up_w   = (const float*)d_in[9];
    const float* gate2_w= (const float*)d_in[10];
    const float* down_w = (const float*)d_in[11];
    const float* ag_w   = (const float*)d_in[12];
    const float* ag_b   = (const float*)d_in[13];
    const float* fg_w   = (const float*)d_in[14];
    const float* fg_b   = (const float*)d_in[15];

    const int GEMM_LDS = 98304;
    const int SW_LDS   = 131072;
    (void)hipFuncSetAttribute(reinterpret_cast<const void*>(&gemm_u<0>),
                              hipFuncAttributeMaxDynamicSharedMemorySize, GEMM_LDS);
    (void)hipFuncSetAttribute(reinterpret_cast<const void*>(&gemm_u<1>),
                              hipFuncAttributeMaxDynamicSharedMemorySize, GEMM_LDS);
    (void)hipFuncSetAttribute(reinterpret_cast<const void*>(&gemm_u<2>),
                              hipFuncAttributeMaxDynamicSharedMemorySize, GEMM_LDS);
    (void)hipFuncSetAttribute(reinterpret_cast<const void*>(&gemm_swiglu),
                              hipFuncAttributeMaxDynamicSharedMemorySize, SW_LDS);

    // ---- workspace regions (peak 251,658,240 B; lifetimes disjoint) ----
    char* ws = (char*)d_ws;
    u16*  Wbuf = (u16*)(ws);                      // 33,554,432 B = 4 DD slots
    u16*  hbuf = (u16*)(ws + 33554432);           // 16,777,216 B
    float* x1  = (float*)(ws + 50331648);         // 33,554,432 B
    u16*  combo= (u16*)(ws + 83886080);           // 67,108,864 B
    char* E    = ws + 150994944;                  // 50,331,648 B
    char* F    = ws + 201326592;                  // 33,554,432 B
    u16*  ffb  = (u16*)(ws + 234881024);          // 16,777,216 B

    u16*   qkvact = (u16*)E;
    float* aof    = (float*)E;
    u16*   aob    = (u16*)(E + 33554432);
    u16*   Wffn2  = (u16*)E;
    u16*   Wdn    = (u16*)E;
    u16*   attnb  = (u16*)F;
    float* fff    = (float*)F;

    float* outp = (float*)d_out;
    const size_t DD = 2048ull * 2048ull;
    const int cg_d = (int)(DD / 4) / 256;
    const int GRID_BIG = 32 * 24;
    const int GRID_SM  = 32 * 8;

    // 1) h = rmsnorm(x, ln1)
    hipLaunchKernelGGL(rmsnorm_k, dim3(4096), dim3(256), 0, stream, x, ln1_w, hbuf);

    // 2) qkv = h @ [Wq;Wk;Wv]^T
    hipLaunchKernelGGL(conv3_bf16, dim3(cg_d, 3), dim3(256), 0, stream,
                       q_w, k_w, v_w, Wbuf, Wbuf + DD, Wbuf + 2 * DD, (int)(DD / 4));
    hipLaunchKernelGGL((gemm_u<0>), dim3(GRID_BIG), dim3(512), GEMM_LDS, stream,
                       hbuf, Wbuf, (float*)nullptr, qkvact,
                       (const float*)nullptr, (const float*)nullptr, (const float*)nullptr,
                       (float*)nullptr, 4096, 6144, 2048, 6144);

    // convert o/ag/fg weights (fg parked at slot 3)
    hipLaunchKernelGGL(conv3_bf16, dim3(cg_d, 3), dim3(256), 0, stream,
                       o_w, ag_w, fg_w, Wbuf, Wbuf + DD, Wbuf + 3 * DD, (int)(DD / 4));

    // 3) l2-normalize q,k (q scaled by temp)
    hipLaunchKernelGGL(qk_l2norm, dim3(32768), dim3(256), 0, stream, qkvact, temp);

    // 4) attention
    hipLaunchKernelGGL(flash_attn, dim3(256), dim3(512), 0, stream, qkvact, attnb);

    // 5) attn_out = attn @ Wo^T
    hipLaunchKernelGGL((gemm_u<1>), dim3(GRID_SM), dim3(512), GEMM_LDS, stream,
                       attnb, Wbuf, aof, aob,
                       (const float*)nullptr, (const float*)nullptr, (const float*)nullptr,
                       (float*)nullptr, 4096, 2048, 2048, 2048);

    // 6) x1 = sigmoid(attn_out@Wag^T + b)*attn_out + (1-g)*x
    hipLaunchKernelGGL((gemm_u<2>), dim3(GRID_SM), dim3(512), GEMM_LDS, stream,
                       aob, Wbuf + DD, (float*)nullptr, (u16*)nullptr,
                       ag_b, aof, x, x1, 4096, 2048, 2048, 2048);

    // 7) h2 = rmsnorm(x1, ln2)
    hipLaunchKernelGGL(rmsnorm_k, dim3(4096), dim3(256), 0, stream, x1, ln2_w, hbuf);

    // 8) FFN: 2 half-dispatches of fused GEMM+SwiGLU (m201 schedule)
    for (int d = 0; d < 2; d++) {
        const size_t w0 = (size_t)(2 * d) * 2048 * 2048;
        const size_t w1 = (size_t)(2 * d + 1) * 2048 * 2048;
        hipLaunchKernelGGL(conv3_bf16, dim3(cg_d, 3), dim3(256), 0, stream,
                           gate_w + w0, up_w + w0, gate2_w + w0,
                           Wbuf, Wbuf + DD, Wbuf + 2 * DD, (int)(DD / 4));
        hipLaunchKernelGGL(conv3_bf16, dim3(cg_d, 3), dim3(256), 0, stream,
                           gate_w + w1, up_w + w1, gate2_w + w1,
                           Wffn2, Wffn2 + DD, Wffn2 + 2 * DD, (int)(DD / 4));
        hipLaunchKernelGGL(gemm_swiglu, dim3(256), dim3(512), SW_LDS, stream,
                           hbuf, Wbuf, Wffn2, combo + (size_t)d * 2 * 2048, 2048);
    }

    // 9) ffn_out = combo @ Wdn^T
    hipLaunchKernelGGL(conv_bf16, dim3(16384), dim3(256), 0, stream, down_w, Wdn, (int)(2048ull * 8192 / 4));
    hipLaunchKernelGGL((gemm_u<1>), dim3(GRID_SM), dim3(512), GEMM_LDS, stream,
                       combo, Wdn, fff, ffb,
                       (const float*)nullptr, (const float*)nullptr, (const float*)nullptr,
                       (float*)nullptr, 4096, 2048, 8192, 2048);

    // 10) out = sigmoid(ffn_out@Wfg^T + b)*ffn_out + (1-g)*x1
    hipLaunchKernelGGL((gemm_u<2>), dim3(GRID_SM), dim3(512), GEMM_LDS, stream,
                       ffb, Wbuf + 3 * DD, (float*)nullptr, (u16*)nullptr,
                       fg_b, fff, x1, outp, 4096, 2048, 2048, 2048);
}

// Round 16
// 1035.950 us; speedup vs baseline: 1.0160x; 1.0160x over previous
//
#include <hip/hip_runtime.h>

typedef unsigned short u16;
typedef unsigned int u32;
using bf16x8 = __attribute__((ext_vector_type(8))) short;
using f32x4  = __attribute__((ext_vector_type(4))) float;

#define EPS 1e-5f

__device__ __forceinline__ u16 f2bf(float f) {
    union { float f; u32 u; } v; v.f = f;
    u32 r = v.u + 0x7FFFu + ((v.u >> 16) & 1u);   // RNE
    return (u16)(r >> 16);
}
__device__ __forceinline__ float bf2f(u16 u) {
    union { u32 u; float f; } v; v.u = ((u32)u) << 16;
    return v.f;
}
__device__ __forceinline__ u32 pack2(float a, float b) {
    return (u32)f2bf(a) | ((u32)f2bf(b) << 16);
}
__device__ __forceinline__ void gl16(const void* g, void* s) {
    __builtin_amdgcn_global_load_lds(
        (const __attribute__((address_space(1))) u32*)g,
        (__attribute__((address_space(3))) u32*)s, 16, 0, 0);
}
__device__ __forceinline__ float sigm(float x) { return 1.f / (1.f + __expf(-x)); }

// ---------------- fp32 -> bf16 convert ----------------
__global__ void conv_bf16(const float* __restrict__ src, u16* __restrict__ dst, int n4) {
    int i = blockIdx.x * 256 + threadIdx.x;
    if (i >= n4) return;
    float4 v = reinterpret_cast<const float4*>(src)[i];
    u32 lo = (u32)f2bf(v.x) | ((u32)f2bf(v.y) << 16);
    u32 hi = (u32)f2bf(v.z) | ((u32)f2bf(v.w) << 16);
    reinterpret_cast<uint2*>(dst)[i] = make_uint2(lo, hi);
}

__global__ void conv3_bf16(const float* __restrict__ s0, const float* __restrict__ s1,
                           const float* __restrict__ s2, u16* __restrict__ d0,
                           u16* __restrict__ d1, u16* __restrict__ d2, int n4) {
    int i = blockIdx.x * 256 + threadIdx.x;
    if (i >= n4) return;
    const float* src = (blockIdx.y == 0) ? s0 : (blockIdx.y == 1) ? s1 : s2;
    u16* dst = (blockIdx.y == 0) ? d0 : (blockIdx.y == 1) ? d1 : d2;
    float4 v = reinterpret_cast<const float4*>(src)[i];
    u32 lo = (u32)f2bf(v.x) | ((u32)f2bf(v.y) << 16);
    u32 hi = (u32)f2bf(v.z) | ((u32)f2bf(v.w) << 16);
    reinterpret_cast<uint2*>(dst)[i] = make_uint2(lo, hi);
}

// ---------------- RMSNorm: fp32 [4096,2048] -> bf16 ----------------
__global__ void rmsnorm_k(const float* __restrict__ x, const float* __restrict__ wt,
                          u16* __restrict__ out) {
    __shared__ float red[4];
    const int row = blockIdx.x, t = threadIdx.x;
    const float* xr = x + (size_t)row * 2048;
    float4 v0 = *reinterpret_cast<const float4*>(&xr[t * 8]);
    float4 v1 = *reinterpret_cast<const float4*>(&xr[t * 8 + 4]);
    float ss = v0.x*v0.x + v0.y*v0.y + v0.z*v0.z + v0.w*v0.w
             + v1.x*v1.x + v1.y*v1.y + v1.z*v1.z + v1.w*v1.w;
#pragma unroll
    for (int d = 1; d < 64; d <<= 1) ss += __shfl_xor(ss, d);
    if ((t & 63) == 0) red[t >> 6] = ss;
    __syncthreads();
    const float tot = red[0] + red[1] + red[2] + red[3];
    const float s = 1.f / sqrtf(tot * (1.f / 2048.f) + EPS);
    float4 w0 = *reinterpret_cast<const float4*>(&wt[t * 8]);
    float4 w1 = *reinterpret_cast<const float4*>(&wt[t * 8 + 4]);
    u32 o[4];
    o[0] = pack2(v0.x * s * w0.x, v0.y * s * w0.y);
    o[1] = pack2(v0.z * s * w0.z, v0.w * s * w0.w);
    o[2] = pack2(v1.x * s * w1.x, v1.y * s * w1.y);
    o[3] = pack2(v1.z * s * w1.z, v1.w * s * w1.w);
    *reinterpret_cast<uint4*>(&out[(size_t)row * 2048 + t * 8]) =
        make_uint4(o[0], o[1], o[2], o[3]);
}

// ---------------- L2 norm of q/k rows (in place); q scaled by temp[h] ----------------
__global__ void qk_l2norm(u16* __restrict__ qkv, const float* __restrict__ temp) {
    const int wid = blockIdx.x * 4 + (threadIdx.x >> 6);
    const int l = threadIdx.x & 63;
    const int n = wid >> 5;
    const int rem = wid & 31;
    const int which = rem >> 4;
    const int h = rem & 15;
    u16* p = qkv + (size_t)n * 6144 + which * 2048 + h * 128 + l * 2;
    u32 v = *reinterpret_cast<const u32*>(p);
    float f0 = bf2f((u16)(v & 0xffff)), f1 = bf2f((u16)(v >> 16));
    float ss = f0 * f0 + f1 * f1;
#pragma unroll
    for (int d = 1; d < 64; d <<= 1) ss += __shfl_xor(ss, d);
    float sc = 1.f / fmaxf(sqrtf(ss), 1e-12f);
    if (which == 0) sc *= temp[h];
    *reinterpret_cast<u32*>(p) = pack2(f0 * sc, f1 * sc);
}

// ================= FFN fused GEMM+SwiGLU (refcheck-proven R12/R14, drain-0) ==============
__global__ __launch_bounds__(512, 1)
void gemm_swiglu(const u16* __restrict__ A, const u16* __restrict__ W0,
                 const u16* __restrict__ W1, u16* __restrict__ combo, int K) {
    extern __shared__ u16 lds[];   // 2 x 32768 u16 = 128 KB
    const int orig = blockIdx.x;
    const int xcd = orig & 7, lin = orig >> 3;
    const int wgid = xcd * 32 + lin;
    const int qsel = wgid & 1;
    const int tix = wgid >> 1;
    const int g = tix >> 5;
    const int rem = tix & 31;
    const int bn = rem >> 2;
    const int bm = (g << 2) + (rem & 3);
    const u16* B = qsel ? W1 : W0;

    const int t = threadIdx.x;
    const int w = t >> 6, l = t & 63;
    const int wr = w >> 2, wc = w & 3;
    const int lr = l & 15, lg = l >> 4;
    const int NT = K >> 6;

    const int srow = t >> 3;
    const int scg  = (t & 7) ^ (srow & 7);
    const u16* aS0 = A + (size_t)(bm * 256 + srow) * K + scg * 8;
    const u16* aS1 = aS0 + (size_t)128 * K;
    const size_t r64 = (size_t)64 * K;

#define STG(slot, src, ko) do {                                     \
        gl16((src) + (ko), (slot) + t * 8);                         \
        gl16((src) + (ko) + r64, (slot) + 4096 + t * 8);            \
    } while (0)

    const int xr = (lr & 7) << 4;
    const int kof[2] = { ((lg) << 4) ^ xr, ((4 + lg) << 4) ^ xr };

    f32x4 acc[8][4];
    u32 pk[8][4][2];

    for (int pan = 0; pan < 3; ++pan) {
        const u16* bS0 = B + (size_t)(pan * 2048 + bn * 256 + srow) * K + scg * 8;
        const u16* bS1 = bS0 + (size_t)128 * K;
        {
            u16* bb = lds;
            STG(bb + 16384, bS0, 0);
            STG(bb + 24576, bS1, 0);
            STG(bb + 0,     aS0, 0);
            STG(bb + 8192,  aS1, 0);
        }
        if (pan == 1) {
#pragma unroll
            for (int m = 0; m < 8; m++)
#pragma unroll
                for (int n = 0; n < 4; n++)
#pragma unroll
                    for (int h = 0; h < 2; h++) {
                        const float a0 = acc[m][n][2 * h], a1 = acc[m][n][2 * h + 1];
                        pk[m][n][h] = pack2(a0 * sigm(a0), a1 * sigm(a1));
                    }
        } else if (pan == 2) {
#pragma unroll
            for (int m = 0; m < 8; m++)
#pragma unroll
                for (int n = 0; n < 4; n++)
#pragma unroll
                    for (int h = 0; h < 2; h++) {
                        const u32 sv = pk[m][n][h];
                        const float t0 = bf2f((u16)(sv & 0xffff)) * acc[m][n][2 * h];
                        const float t1 = bf2f((u16)(sv >> 16)) * acc[m][n][2 * h + 1];
                        pk[m][n][h] = pack2(t0, t1);
                    }
        }
        asm volatile("s_waitcnt vmcnt(0)" ::: "memory");
        __builtin_amdgcn_s_barrier();

#pragma unroll
        for (int i = 0; i < 8; i++)
#pragma unroll
            for (int j = 0; j < 4; j++) acc[i][j] = (f32x4){0.f, 0.f, 0.f, 0.f};

        for (int T = 0; T < NT; ++T) {
            const char* base = (const char*)lds + (size_t)(T & 1) * 65536;
            u16* sb = lds + ((T + 1) & 1) * 32768;
            const bool st = (T + 1) < NT;
            const size_t ko = (size_t)(T + 1) * 64;
            const char* aB = base + wr * 16384;
            const char* bB = base + 32768 + (wc >> 1) * 16384 + (wc & 1) * 8192;
            bf16x8 bfr[4][2];
#pragma unroll
            for (int n = 0; n < 4; n++) {
                const int rb = n * 16 + lr;
                bfr[n][0] = *reinterpret_cast<const bf16x8*>(bB + rb * 128 + kof[0]);
                bfr[n][1] = *reinterpret_cast<const bf16x8*>(bB + rb * 128 + kof[1]);
            }
#pragma unroll
            for (int p = 0; p < 4; ++p) {
                const int ks = p >> 1, mh = p & 1;
                bf16x8 af[4];
#pragma unroll
                for (int m2 = 0; m2 < 4; m2++) {
                    const int ra = mh * 64 + m2 * 16 + lr;
                    af[m2] = *reinterpret_cast<const bf16x8*>(aB + ra * 128 + kof[ks]);
                }
                if (st) {
                    if (p == 0) STG(sb + 16384, bS0, ko);
                    if (p == 1) STG(sb + 24576, bS1, ko);
                    if (p == 2) STG(sb + 0,     aS0, ko);
                    if (p == 3) STG(sb + 8192,  aS1, ko);
                }
                __builtin_amdgcn_s_setprio(1);
#pragma unroll
                for (int m2 = 0; m2 < 4; m2++)
#pragma unroll
                    for (int n = 0; n < 4; n++)
                        acc[mh * 4 + m2][n] = __builtin_amdgcn_mfma_f32_16x16x32_bf16(
                            af[m2], bfr[n][ks], acc[mh * 4 + m2][n], 0, 0, 0);
                __builtin_amdgcn_s_setprio(0);
            }
            if (st) {
                asm volatile("s_waitcnt vmcnt(0)" ::: "memory");
                __builtin_amdgcn_s_barrier();
            }
        }
    }
#undef STG

    const int cbase = qsel * 2048 + bn * 256;
#pragma unroll
    for (int m = 0; m < 8; m++) {
        const int row = bm * 256 + wr * 128 + m * 16 + lg * 4;
#pragma unroll
        for (int n = 0; n < 4; n++) {
            const int col = cbase + wc * 64 + n * 16 + lr;
#pragma unroll
            for (int h = 0; h < 2; h++) {
                const u32 tv = pk[m][n][h];
                const float o0 = bf2f((u16)(tv & 0xffff)) * sigm(acc[m][n][2 * h]);
                const float o1 = bf2f((u16)(tv >> 16)) * sigm(acc[m][n][2 * h + 1]);
                combo[(size_t)(row + 2 * h) * 8192 + col] = f2bf(o0);
                combo[(size_t)(row + 2 * h + 1) * 8192 + col] = f2bf(o1);
            }
        }
    }
}

// ================= unified NT GEMM: 128x256, BK=64, 1 barrier per K-tile =================
template <int EPI>
__global__ __launch_bounds__(512, 1)
void gemm_u(const u16* __restrict__ A, const u16* __restrict__ B,
            float* __restrict__ outF, u16* __restrict__ outB,
            const float* __restrict__ bias, const float* __restrict__ addend,
            const float* __restrict__ resid, float* __restrict__ outG,
            int M, int N, int K, int ldc) {
    extern __shared__ u16 lds[];   // 2 bufs x 24576 u16 = 98304 B
    const int nbn = N >> 8;
    const int nwg = (M >> 7) * nbn;
    const int orig = blockIdx.x;
    const int q8 = nwg >> 3, r8 = nwg & 7;
    const int xcd = orig & 7, lin = orig >> 3;
    const int wgid = (xcd < r8 ? xcd * (q8 + 1) : r8 * (q8 + 1) + (xcd - r8) * q8) + lin;
    const int g = wgid / (nbn << 3);
    const int rem = wgid - g * (nbn << 3);
    const int bn = rem >> 3;
    const int bm = (g << 3) + (rem & 7);

    const int t = threadIdx.x;
    const int w = t >> 6, l = t & 63;
    const int wr = w >> 2, wc = w & 3;
    const int lr = l & 15, lg = l >> 4;
    const int NT = K >> 6;

    const int pr = t >> 3, ps = t & 7;
    const int sg = ps ^ (pr & 7);
    const u16* aSrc = A + (size_t)(bm * 128 + pr) * K + sg * 8;
    const u16* bSrc = B + (size_t)(bn * 256 + pr) * K + sg * 8;
    const size_t rowStep = (size_t)64 * K;

#define STG_A(bi, ko) do { u16* da = lds + (bi) * 24576 + t * 8;                 \
        gl16(aSrc + (ko), da); gl16(aSrc + rowStep + (ko), da + 4096); } while (0)
#define STG_B01(bi, ko) do { u16* db = lds + (bi) * 24576 + 8192 + t * 8;        \
        gl16(bSrc + (ko), db); gl16(bSrc + rowStep + (ko), db + 4096); } while (0)
#define STG_B23(bi, ko) do { u16* db = lds + (bi) * 24576 + 8192 + t * 8;        \
        gl16(bSrc + 2 * rowStep + (ko), db + 8192);                              \
        gl16(bSrc + 3 * rowStep + (ko), db + 12288); } while (0)

    f32x4 acc[4][4];
#pragma unroll
    for (int i = 0; i < 4; i++)
#pragma unroll
        for (int j = 0; j < 4; j++) acc[i][j] = (f32x4){0.f, 0.f, 0.f, 0.f};

    const int xr = (lr & 7) << 4;
    const int kof[2] = { ((lg) << 4) ^ xr, ((4 + lg) << 4) ^ xr };

    STG_A(0, 0); STG_B01(0, 0); STG_B23(0, 0);
    asm volatile("s_waitcnt vmcnt(0)" ::: "memory");
    __builtin_amdgcn_s_barrier();

    for (int T = 0; T < NT; ++T) {
        const char* bufA = (const char*)lds + (size_t)(T & 1) * 49152;
        const char* bufB = bufA + 16384;
        const int sbi = (T + 1) & 1;
        const bool st = (T + 1) < NT;
        const size_t ko = (size_t)(T + 1) * 64;
        bf16x8 bf[4][2];
#pragma unroll
        for (int n = 0; n < 4; n++) {
            const int rb = wc * 64 + n * 16 + lr;
            bf[n][0] = *reinterpret_cast<const bf16x8*>(bufB + rb * 128 + kof[0]);
            bf[n][1] = *reinterpret_cast<const bf16x8*>(bufB + rb * 128 + kof[1]);
        }
#pragma unroll
        for (int p = 0; p < 4; ++p) {
            const int ks = p >> 1, mh = p & 1;
            bf16x8 af[2];
#pragma unroll
            for (int m2 = 0; m2 < 2; m2++) {
                const int ra = wr * 64 + (mh * 2 + m2) * 16 + lr;
                af[m2] = *reinterpret_cast<const bf16x8*>(bufA + ra * 128 + kof[ks]);
            }
            if (st) {
                if (p == 0) STG_A(sbi, ko);
                if (p == 1) STG_B01(sbi, ko);
                if (p == 2) STG_B23(sbi, ko);
            }
            __builtin_amdgcn_s_setprio(1);
#pragma unroll
            for (int m2 = 0; m2 < 2; m2++)
#pragma unroll
                for (int n = 0; n < 4; n++)
                    acc[mh * 2 + m2][n] = __builtin_amdgcn_mfma_f32_16x16x32_bf16(
                        af[m2], bf[n][ks], acc[mh * 2 + m2][n], 0, 0, 0);
            __builtin_amdgcn_s_setprio(0);
        }
        if (st) {
            asm volatile("s_waitcnt vmcnt(0)" ::: "memory");
            __builtin_amdgcn_s_barrier();
        }
    }
#undef STG_A
#undef STG_B01
#undef STG_B23

#pragma unroll
    for (int m = 0; m < 4; m++) {
        const int row = bm * 128 + wr * 64 + m * 16 + lg * 4;
#pragma unroll
        for (int n = 0; n < 4; n++) {
            const int col = bn * 256 + wc * 64 + n * 16 + lr;
#pragma unroll
            for (int q = 0; q < 4; q++) {
                const size_t idx = (size_t)(row + q) * ldc + col;
                const float v = acc[m][n][q];
                if (EPI == 0) {
                    outB[idx] = f2bf(v);
                } else if (EPI == 1) {
                    outF[idx] = v;
                    outB[idx] = f2bf(v);
                } else {
                    const float g2 = sigm(v + bias[col]);
                    outG[idx] = g2 * addend[idx] + (1.f - g2) * resid[idx];
                }
            }
        }
    }
}

// ---------------- causal flash attention (QBLK=128, 8 waves, reg-staged dbuf) ----------------
#define VSWZ(dh) (((((dh) >> 3) ^ (dh)) & 7) << 4)
__global__ __launch_bounds__(512) void flash_attn(const u16* __restrict__ qkv,
                                                  u16* __restrict__ out) {
    __shared__ u16 klds[2][64 * 128];
    __shared__ u16 vlds[2][128 * 64];
    __shared__ u16 plds[8][16 * 64];
    const int t = threadIdx.x, w = t >> 6, l = t & 63;
    const int lr = l & 15, lg = l >> 4;
    const int b0 = blockIdx.x;
    const int xcd = b0 & 7, i0 = b0 >> 3;
    const int bh = ((i0 & 3) << 3) | xcd;
    const int p = i0 >> 2;
    const int b = bh >> 4, h = bh & 15;
    const size_t base = (size_t)b * 2048;
    const int sr0 = t >> 4;
    const int sc0 = (t & 15) << 3;

    uint4 kreg0, kreg1, vreg0, vreg1;

#define STAGE_LOAD(KT) do {                                                          \
        const size_t gg = (base + (size_t)(KT) * 64 + sr0) * 6144 + h * 128 + sc0;   \
        kreg0 = *reinterpret_cast<const uint4*>(&qkv[gg + 2048]);                    \
        vreg0 = *reinterpret_cast<const uint4*>(&qkv[gg + 4096]);                    \
        kreg1 = *reinterpret_cast<const uint4*>(&qkv[gg + 32 * 6144 + 2048]);        \
        vreg1 = *reinterpret_cast<const uint4*>(&qkv[gg + 32 * 6144 + 4096]);        \
    } while (0)

#define STAGE_WRITE(BUF) do {                                                                     \
        char* kb = (char*)&klds[BUF][0];                                                          \
        char* vb = (char*)&vlds[BUF][0];                                                          \
        *reinterpret_cast<uint4*>(kb + ((sr0 * 256 + sc0 * 2) ^ ((sr0 & 7) << 4))) = kreg0;       \
        *reinterpret_cast<uint4*>(kb + (((sr0 + 32) * 256 + sc0 * 2) ^ ((sr0 & 7) << 4))) = kreg1;\
        union { uint4 u; u16 s[8]; } vv;                                                          \
        vv.u = vreg0;                                                                             \
        _Pragma("unroll")                                                                         \
        for (int jj = 0; jj < 8; jj++) {                                                          \
            const int dh = sc0 + jj;                                                              \
            *reinterpret_cast<u16*>(vb + ((dh * 128 + sr0 * 2) ^ VSWZ(dh))) = vv.s[jj];           \
        }                                                                                         \
        vv.u = vreg1;                                                                             \
        _Pragma("unroll")                                                                         \
        for (int jj = 0; jj < 8; jj++) {                                                          \
            const int dh = sc0 + jj;                                                              \
            *reinterpret_cast<u16*>(vb + ((dh * 128 + (sr0 + 32) * 2) ^ VSWZ(dh))) = vv.s[jj];    \
        }                                                                                         \
    } while (0)

    for (int phase = 0; phase < 2; ++phase) {
        const int qt = phase ? (15 - p) : p;
        const int last = 2 * qt + 1;
        const int qrow = qt * 128 + w * 16 + lr;
        const int qr0 = qt * 128 + w * 16 + lg * 4;
        bf16x8 qf[4];
#pragma unroll
        for (int kk = 0; kk < 4; kk++)
            qf[kk] = *reinterpret_cast<const bf16x8*>(
                &qkv[(base + qrow) * 6144 + h * 128 + kk * 32 + lg * 8]);
        f32x4 o[8];
#pragma unroll
        for (int i = 0; i < 8; i++) o[i] = (f32x4){0.f, 0.f, 0.f, 0.f};
        float m[4] = {-1e30f, -1e30f, -1e30f, -1e30f};
        float ls[4] = {0.f, 0.f, 0.f, 0.f};

        STAGE_LOAD(0);
        int cur = 0;
        STAGE_WRITE(0);
        __syncthreads();

        for (int kt = 0; kt <= last; ++kt) {
            if (kt < last) STAGE_LOAD(kt + 1);
            const char* kb = (const char*)&klds[cur][0];
            const char* vb = (const char*)&vlds[cur][0];
            f32x4 s[4];
#pragma unroll
            for (int nf = 0; nf < 4; nf++) {
                f32x4 a = (f32x4){0.f, 0.f, 0.f, 0.f};
                const int kv = nf * 16 + lr;
#pragma unroll
                for (int kk = 0; kk < 4; kk++) {
                    bf16x8 kf = *reinterpret_cast<const bf16x8*>(
                        kb + ((kv * 256 + kk * 64 + lg * 16) ^ ((kv & 7) << 4)));
                    a = __builtin_amdgcn_mfma_f32_16x16x32_bf16(qf[kk], kf, a, 0, 0, 0);
                }
                s[nf] = a;
            }
            if (kt >= 2 * qt) {
#pragma unroll
                for (int nf = 0; nf < 4; nf++) {
                    const int kvi = kt * 64 + nf * 16 + lr;
#pragma unroll
                    for (int q = 0; q < 4; q++)
                        if (kvi > qr0 + q) s[nf][q] = -1e30f;
                }
            }
            float mx[4] = {-1e30f, -1e30f, -1e30f, -1e30f};
#pragma unroll
            for (int nf = 0; nf < 4; nf++)
#pragma unroll
                for (int q = 0; q < 4; q++) mx[q] = fmaxf(mx[q], s[nf][q]);
#pragma unroll
            for (int q = 0; q < 4; q++) {
#pragma unroll
                for (int d = 1; d < 16; d <<= 1) mx[q] = fmaxf(mx[q], __shfl_xor(mx[q], d));
            }
            float fac[4], rs[4];
#pragma unroll
            for (int q = 0; q < 4; q++) {
                const float mn = fmaxf(m[q], mx[q]);
                fac[q] = __expf(m[q] - mn);
                m[q] = mn;
                rs[q] = 0.f;
            }
#pragma unroll
            for (int nf = 0; nf < 4; nf++) {
#pragma unroll
                for (int q = 0; q < 4; q++) {
                    const float pv = __expf(s[nf][q] - m[q]);
                    s[nf][q] = pv;
                    rs[q] += pv;
                }
            }
#pragma unroll
            for (int nf = 0; nf < 4; nf++) {
                const int col = nf * 16 + lr;
#pragma unroll
                for (int q = 0; q < 4; q++) {
                    const int row = lg * 4 + q;
                    *reinterpret_cast<u16*>((char*)&plds[w][0] +
                        ((row * 128 + col * 2) ^ ((row & 7) << 4))) = f2bf(s[nf][q]);
                }
            }
#pragma unroll
            for (int q = 0; q < 4; q++) {
#pragma unroll
                for (int d = 1; d < 16; d <<= 1) rs[q] += __shfl_xor(rs[q], d);
                ls[q] = ls[q] * fac[q] + rs[q];
            }
#pragma unroll
            for (int nf2 = 0; nf2 < 8; nf2++)
#pragma unroll
                for (int q = 0; q < 4; q++) o[nf2][q] *= fac[q];
#pragma unroll
            for (int ks = 0; ks < 2; ks++) {
                bf16x8 pf = *reinterpret_cast<const bf16x8*>((char*)&plds[w][0] +
                    ((lr * 128 + ks * 64 + lg * 16) ^ ((lr & 7) << 4)));
#pragma unroll
                for (int nf2 = 0; nf2 < 8; nf2++) {
                    const int dh = nf2 * 16 + lr;
                    bf16x8 vf = *reinterpret_cast<const bf16x8*>(
                        vb + ((dh * 128 + ks * 64 + lg * 16) ^ VSWZ(dh)));
                    o[nf2] = __builtin_amdgcn_mfma_f32_16x16x32_bf16(pf, vf, o[nf2], 0, 0, 0);
                }
            }
            if (kt < last) STAGE_WRITE(cur ^ 1);
            __syncthreads();
            cur ^= 1;
        }
#pragma unroll
        for (int nf2 = 0; nf2 < 8; nf2++) {
            const int col = h * 128 + nf2 * 16 + lr;
#pragma unroll
            for (int q = 0; q < 4; q++) {
                const float v = o[nf2][q] / ls[q];
                out[(base + qr0 + q) * 2048 + col] = f2bf(v);
            }
        }
        __syncthreads();
    }
#undef STAGE_LOAD
#undef STAGE_WRITE
}

// ---------------- launch ----------------
extern "C" void kernel_launch(void* const* d_in, const int* in_sizes, int n_in,
                              void* d_out, int out_size, void* d_ws, size_t ws_size,
                              hipStream_t stream) {
    const float* x      = (const float*)d_in[0];
    const float* q_w    = (const float*)d_in[1];
    const float* k_w    = (const float*)d_in[2];
    const float* v_w    = (const float*)d_in[3];
    const float* o_w    = (const float*)d_in[4];
    const float* temp   = (const float*)d_in[5];
    const float* ln1_w  = (const float*)d_in[6];
    const float* ln2_w  = (const float*)d_in[7];
    const float* gate_w = (const float*)d_in[8];
    const float* up_w   = (const float*)d_in[9];
    const float* gate2_w= (const float*)d_in[10];
    const float* down_w = (const float*)d_in[11];
    const float* ag_w   = (const float*)d_in[12];
    const float* ag_b   = (const float*)d_in[13];
    const float* fg_w   = (const float*)d_in[14];
    const float* fg_b   = (const float*)d_in[15];

    const int GEMM_LDS = 98304;
    const int SW_LDS   = 131072;
    (void)hipFuncSetAttribute(reinterpret_cast<const void*>(&gemm_u<0>),
                              hipFuncAttributeMaxDynamicSharedMemorySize, GEMM_LDS);
    (void)hipFuncSetAttribute(reinterpret_cast<const void*>(&gemm_u<1>),
                              hipFuncAttributeMaxDynamicSharedMemorySize, GEMM_LDS);
    (void)hipFuncSetAttribute(reinterpret_cast<const void*>(&gemm_u<2>),
                              hipFuncAttributeMaxDynamicSharedMemorySize, GEMM_LDS);
    (void)hipFuncSetAttribute(reinterpret_cast<const void*>(&gemm_swiglu),
                              hipFuncAttributeMaxDynamicSharedMemorySize, SW_LDS);

    // ---- workspace regions (peak 251,658,240 B; lifetimes disjoint) ----
    char* ws = (char*)d_ws;
    u16*  Wbuf = (u16*)(ws);                      // 33,554,432 B = 4 DD slots
    u16*  hbuf = (u16*)(ws + 33554432);           // 16,777,216 B
    float* x1  = (float*)(ws + 50331648);         // 33,554,432 B
    u16*  combo= (u16*)(ws + 83886080);           // 67,108,864 B
    char* E    = ws + 150994944;                  // 50,331,648 B
    char* F    = ws + 201326592;                  // 33,554,432 B
    u16*  ffb  = (u16*)(ws + 234881024);          // 16,777,216 B

    u16*   qkvact = (u16*)E;
    float* aof    = (float*)E;
    u16*   aob    = (u16*)(E + 33554432);
    u16*   Wffn2  = (u16*)E;
    u16*   Wdn    = (u16*)E;
    u16*   attnb  = (u16*)F;
    float* fff    = (float*)F;

    float* outp = (float*)d_out;
    const size_t DD = 2048ull * 2048ull;
    const int cg_d = (int)(DD / 4) / 256;
    const int GRID_BIG = 32 * 24;
    const int GRID_SM  = 32 * 8;

    // 1) h = rmsnorm(x, ln1)
    hipLaunchKernelGGL(rmsnorm_k, dim3(4096), dim3(256), 0, stream, x, ln1_w, hbuf);

    // 2) qkv = h @ [Wq;Wk;Wv]^T
    hipLaunchKernelGGL(conv3_bf16, dim3(cg_d, 3), dim3(256), 0, stream,
                       q_w, k_w, v_w, Wbuf, Wbuf + DD, Wbuf + 2 * DD, (int)(DD / 4));
    hipLaunchKernelGGL((gemm_u<0>), dim3(GRID_BIG), dim3(512), GEMM_LDS, stream,
                       hbuf, Wbuf, (float*)nullptr, qkvact,
                       (const float*)nullptr, (const float*)nullptr, (const float*)nullptr,
                       (float*)nullptr, 4096, 6144, 2048, 6144);

    // convert o/ag/fg weights (fg parked at slot 3)
    hipLaunchKernelGGL(conv3_bf16, dim3(cg_d, 3), dim3(256), 0, stream,
                       o_w, ag_w, fg_w, Wbuf, Wbuf + DD, Wbuf + 3 * DD, (int)(DD / 4));

    // 3) l2-normalize q,k (q scaled by temp)
    hipLaunchKernelGGL(qk_l2norm, dim3(32768), dim3(256), 0, stream, qkvact, temp);

    // 4) attention
    hipLaunchKernelGGL(flash_attn, dim3(256), dim3(512), 0, stream, qkvact, attnb);

    // 5) attn_out = attn @ Wo^T
    hipLaunchKernelGGL((gemm_u<1>), dim3(GRID_SM), dim3(512), GEMM_LDS, stream,
                       attnb, Wbuf, aof, aob,
                       (const float*)nullptr, (const float*)nullptr, (const float*)nullptr,
                       (float*)nullptr, 4096, 2048, 2048, 2048);

    // 6) x1 = sigmoid(attn_out@Wag^T + b)*attn_out + (1-g)*x
    hipLaunchKernelGGL((gemm_u<2>), dim3(GRID_SM), dim3(512), GEMM_LDS, stream,
                       aob, Wbuf + DD, (float*)nullptr, (u16*)nullptr,
                       ag_b, aof, x, x1, 4096, 2048, 2048, 2048);

    // 7) h2 = rmsnorm(x1, ln2)
    hipLaunchKernelGGL(rmsnorm_k, dim3(4096), dim3(256), 0, stream, x1, ln2_w, hbuf);

    // 8) FFN: 2 half-dispatches of fused GEMM+SwiGLU
    for (int d = 0; d < 2; d++) {
        const size_t w0 = (size_t)(2 * d) * 2048 * 2048;
        const size_t w1 = (size_t)(2 * d + 1) * 2048 * 2048;
        hipLaunchKernelGGL(conv3_bf16, dim3(cg_d, 3), dim3(256), 0, stream,
                           gate_w + w0, up_w + w0, gate2_w + w0,
                           Wbuf, Wbuf + DD, Wbuf + 2 * DD, (int)(DD / 4));
        hipLaunchKernelGGL(conv3_bf16, dim3(cg_d, 3), dim3(256), 0, stream,
                           gate_w + w1, up_w + w1, gate2_w + w1,
                           Wffn2, Wffn2 + DD, Wffn2 + 2 * DD, (int)(DD / 4));
        hipLaunchKernelGGL(gemm_swiglu, dim3(256), dim3(512), SW_LDS, stream,
                           hbuf, Wbuf, Wffn2, combo + (size_t)d * 2 * 2048, 2048);
    }

    // 9) ffn_out = combo @ Wdn^T
    hipLaunchKernelGGL(conv_bf16, dim3(16384), dim3(256), 0, stream, down_w, Wdn, (int)(2048ull * 8192 / 4));
    hipLaunchKernelGGL((gemm_u<1>), dim3(GRID_SM), dim3(512), GEMM_LDS, stream,
                       combo, Wdn, fff, ffb,
                       (const float*)nullptr, (const float*)nullptr, (const float*)nullptr,
                       (float*)nullptr, 4096, 2048, 8192, 2048);

    // 10) out = sigmoid(ffn_out@Wfg^T + b)*ffn_out + (1-g)*x1
    hipLaunchKernelGGL((gemm_u<2>), dim3(GRID_SM), dim3(512), GEMM_LDS, stream,
                       ffb, Wbuf + 3 * DD, (float*)nullptr, (u16*)nullptr,
                       fg_b, fff, x1, outp, 4096, 2048, 2048, 2048);
}

// Round 17
// 1030.694 us; speedup vs baseline: 1.0212x; 1.0051x over previous
//
#include <hip/hip_runtime.h>

typedef unsigned short u16;
typedef unsigned int u32;
using bf16x8 = __attribute__((ext_vector_type(8))) short;
using f32x4  = __attribute__((ext_vector_type(4))) float;

#define EPS 1e-5f

__device__ __forceinline__ u16 f2bf(float f) {
    union { float f; u32 u; } v; v.f = f;
    u32 r = v.u + 0x7FFFu + ((v.u >> 16) & 1u);   // RNE
    return (u16)(r >> 16);
}
__device__ __forceinline__ float bf2f(u16 u) {
    union { u32 u; float f; } v; v.u = ((u32)u) << 16;
    return v.f;
}
__device__ __forceinline__ u32 pack2(float a, float b) {
    return (u32)f2bf(a) | ((u32)f2bf(b) << 16);
}
__device__ __forceinline__ void gl16(const void* g, void* s) {
    __builtin_amdgcn_global_load_lds(
        (const __attribute__((address_space(1))) u32*)g,
        (__attribute__((address_space(3))) u32*)s, 16, 0, 0);
}
__device__ __forceinline__ float sigm(float x) { return 1.f / (1.f + __expf(-x)); }

// ---------------- fp32 -> bf16 convert ----------------
__global__ void conv_bf16(const float* __restrict__ src, u16* __restrict__ dst, int n4) {
    int i = blockIdx.x * 256 + threadIdx.x;
    if (i >= n4) return;
    float4 v = reinterpret_cast<const float4*>(src)[i];
    u32 lo = (u32)f2bf(v.x) | ((u32)f2bf(v.y) << 16);
    u32 hi = (u32)f2bf(v.z) | ((u32)f2bf(v.w) << 16);
    reinterpret_cast<uint2*>(dst)[i] = make_uint2(lo, hi);
}

__global__ void conv3_bf16(const float* __restrict__ s0, const float* __restrict__ s1,
                           const float* __restrict__ s2, u16* __restrict__ d0,
                           u16* __restrict__ d1, u16* __restrict__ d2, int n4) {
    int i = blockIdx.x * 256 + threadIdx.x;
    if (i >= n4) return;
    const float* src = (blockIdx.y == 0) ? s0 : (blockIdx.y == 1) ? s1 : s2;
    u16* dst = (blockIdx.y == 0) ? d0 : (blockIdx.y == 1) ? d1 : d2;
    float4 v = reinterpret_cast<const float4*>(src)[i];
    u32 lo = (u32)f2bf(v.x) | ((u32)f2bf(v.y) << 16);
    u32 hi = (u32)f2bf(v.z) | ((u32)f2bf(v.w) << 16);
    reinterpret_cast<uint2*>(dst)[i] = make_uint2(lo, hi);
}

// 6-slice variant: converts both FFN quarters' (gate|up|gate2) in ONE launch.
// y in [0,6): y<3 -> quarter q0 slice y into dA + y*DD; else quarter q1 slice (y-3) into dB.
__global__ void conv6_bf16(const float* __restrict__ gate, const float* __restrict__ up,
                           const float* __restrict__ gate2, u16* __restrict__ dA,
                           u16* __restrict__ dB, size_t ofs0, size_t ofs1, int n4) {
    int i = blockIdx.x * 256 + threadIdx.x;
    if (i >= n4) return;
    const int y = blockIdx.y;
    const int sl = (y < 3) ? y : (y - 3);
    const float* base = (sl == 0) ? gate : (sl == 1) ? up : gate2;
    const float* src = base + ((y < 3) ? ofs0 : ofs1);
    u16* dst = ((y < 3) ? dA : dB) + (size_t)sl * 2048 * 2048;
    float4 v = reinterpret_cast<const float4*>(src)[i];
    u32 lo = (u32)f2bf(v.x) | ((u32)f2bf(v.y) << 16);
    u32 hi = (u32)f2bf(v.z) | ((u32)f2bf(v.w) << 16);
    reinterpret_cast<uint2*>(dst)[i] = make_uint2(lo, hi);
}

// ---------------- RMSNorm: fp32 [4096,2048] -> bf16 ----------------
__global__ void rmsnorm_k(const float* __restrict__ x, const float* __restrict__ wt,
                          u16* __restrict__ out) {
    __shared__ float red[4];
    const int row = blockIdx.x, t = threadIdx.x;
    const float* xr = x + (size_t)row * 2048;
    float4 v0 = *reinterpret_cast<const float4*>(&xr[t * 8]);
    float4 v1 = *reinterpret_cast<const float4*>(&xr[t * 8 + 4]);
    float ss = v0.x*v0.x + v0.y*v0.y + v0.z*v0.z + v0.w*v0.w
             + v1.x*v1.x + v1.y*v1.y + v1.z*v1.z + v1.w*v1.w;
#pragma unroll
    for (int d = 1; d < 64; d <<= 1) ss += __shfl_xor(ss, d);
    if ((t & 63) == 0) red[t >> 6] = ss;
    __syncthreads();
    const float tot = red[0] + red[1] + red[2] + red[3];
    const float s = 1.f / sqrtf(tot * (1.f / 2048.f) + EPS);
    float4 w0 = *reinterpret_cast<const float4*>(&wt[t * 8]);
    float4 w1 = *reinterpret_cast<const float4*>(&wt[t * 8 + 4]);
    u32 o[4];
    o[0] = pack2(v0.x * s * w0.x, v0.y * s * w0.y);
    o[1] = pack2(v0.z * s * w0.z, v0.w * s * w0.w);
    o[2] = pack2(v1.x * s * w1.x, v1.y * s * w1.y);
    o[3] = pack2(v1.z * s * w1.z, v1.w * s * w1.w);
    *reinterpret_cast<uint4*>(&out[(size_t)row * 2048 + t * 8]) =
        make_uint4(o[0], o[1], o[2], o[3]);
}

// ---------------- L2 norm of q/k rows (in place); q scaled by temp[h] ----------------
__global__ void qk_l2norm(u16* __restrict__ qkv, const float* __restrict__ temp) {
    const int wid = blockIdx.x * 4 + (threadIdx.x >> 6);
    const int l = threadIdx.x & 63;
    const int n = wid >> 5;
    const int rem = wid & 31;
    const int which = rem >> 4;
    const int h = rem & 15;
    u16* p = qkv + (size_t)n * 6144 + which * 2048 + h * 128 + l * 2;
    u32 v = *reinterpret_cast<const u32*>(p);
    float f0 = bf2f((u16)(v & 0xffff)), f1 = bf2f((u16)(v >> 16));
    float ss = f0 * f0 + f1 * f1;
#pragma unroll
    for (int d = 1; d < 64; d <<= 1) ss += __shfl_xor(ss, d);
    float sc = 1.f / fmaxf(sqrtf(ss), 1e-12f);
    if (which == 0) sc *= temp[h];
    *reinterpret_cast<u32*>(p) = pack2(f0 * sc, f1 * sc);
}

// ================= FFN fused GEMM+SwiGLU (refcheck-proven R12/R14, drain-0) ==============
__global__ __launch_bounds__(512, 1)
void gemm_swiglu(const u16* __restrict__ A, const u16* __restrict__ W0,
                 const u16* __restrict__ W1, u16* __restrict__ combo, int K) {
    extern __shared__ u16 lds[];   // 2 x 32768 u16 = 128 KB
    const int orig = blockIdx.x;
    const int xcd = orig & 7, lin = orig >> 3;
    const int wgid = xcd * 32 + lin;
    const int qsel = wgid & 1;
    const int tix = wgid >> 1;
    const int g = tix >> 5;
    const int rem = tix & 31;
    const int bn = rem >> 2;
    const int bm = (g << 2) + (rem & 3);
    const u16* B = qsel ? W1 : W0;

    const int t = threadIdx.x;
    const int w = t >> 6, l = t & 63;
    const int wr = w >> 2, wc = w & 3;
    const int lr = l & 15, lg = l >> 4;
    const int NT = K >> 6;

    const int srow = t >> 3;
    const int scg  = (t & 7) ^ (srow & 7);
    const u16* aS0 = A + (size_t)(bm * 256 + srow) * K + scg * 8;
    const u16* aS1 = aS0 + (size_t)128 * K;
    const size_t r64 = (size_t)64 * K;

#define STG(slot, src, ko) do {                                     \
        gl16((src) + (ko), (slot) + t * 8);                         \
        gl16((src) + (ko) + r64, (slot) + 4096 + t * 8);            \
    } while (0)

    const int xr = (lr & 7) << 4;
    const int kof[2] = { ((lg) << 4) ^ xr, ((4 + lg) << 4) ^ xr };

    f32x4 acc[8][4];
    u32 pk[8][4][2];

    for (int pan = 0; pan < 3; ++pan) {
        const u16* bS0 = B + (size_t)(pan * 2048 + bn * 256 + srow) * K + scg * 8;
        const u16* bS1 = bS0 + (size_t)128 * K;
        {
            u16* bb = lds;
            STG(bb + 16384, bS0, 0);
            STG(bb + 24576, bS1, 0);
            STG(bb + 0,     aS0, 0);
            STG(bb + 8192,  aS1, 0);
        }
        if (pan == 1) {
#pragma unroll
            for (int m = 0; m < 8; m++)
#pragma unroll
                for (int n = 0; n < 4; n++)
#pragma unroll
                    for (int h = 0; h < 2; h++) {
                        const float a0 = acc[m][n][2 * h], a1 = acc[m][n][2 * h + 1];
                        pk[m][n][h] = pack2(a0 * sigm(a0), a1 * sigm(a1));
                    }
        } else if (pan == 2) {
#pragma unroll
            for (int m = 0; m < 8; m++)
#pragma unroll
                for (int n = 0; n < 4; n++)
#pragma unroll
                    for (int h = 0; h < 2; h++) {
                        const u32 sv = pk[m][n][h];
                        const float t0 = bf2f((u16)(sv & 0xffff)) * acc[m][n][2 * h];
                        const float t1 = bf2f((u16)(sv >> 16)) * acc[m][n][2 * h + 1];
                        pk[m][n][h] = pack2(t0, t1);
                    }
        }
        asm volatile("s_waitcnt vmcnt(0)" ::: "memory");
        __builtin_amdgcn_s_barrier();

#pragma unroll
        for (int i = 0; i < 8; i++)
#pragma unroll
            for (int j = 0; j < 4; j++) acc[i][j] = (f32x4){0.f, 0.f, 0.f, 0.f};

        for (int T = 0; T < NT; ++T) {
            const char* base = (const char*)lds + (size_t)(T & 1) * 65536;
            u16* sb = lds + ((T + 1) & 1) * 32768;
            const bool st = (T + 1) < NT;
            const size_t ko = (size_t)(T + 1) * 64;
            const char* aB = base + wr * 16384;
            const char* bB = base + 32768 + (wc >> 1) * 16384 + (wc & 1) * 8192;
            bf16x8 bfr[4][2];
#pragma unroll
            for (int n = 0; n < 4; n++) {
                const int rb = n * 16 + lr;
                bfr[n][0] = *reinterpret_cast<const bf16x8*>(bB + rb * 128 + kof[0]);
                bfr[n][1] = *reinterpret_cast<const bf16x8*>(bB + rb * 128 + kof[1]);
            }
#pragma unroll
            for (int p = 0; p < 4; ++p) {
                const int ks = p >> 1, mh = p & 1;
                bf16x8 af[4];
#pragma unroll
                for (int m2 = 0; m2 < 4; m2++) {
                    const int ra = mh * 64 + m2 * 16 + lr;
                    af[m2] = *reinterpret_cast<const bf16x8*>(aB + ra * 128 + kof[ks]);
                }
                if (st) {
                    if (p == 0) STG(sb + 16384, bS0, ko);
                    if (p == 1) STG(sb + 24576, bS1, ko);
                    if (p == 2) STG(sb + 0,     aS0, ko);
                    if (p == 3) STG(sb + 8192,  aS1, ko);
                }
                __builtin_amdgcn_s_setprio(1);
#pragma unroll
                for (int m2 = 0; m2 < 4; m2++)
#pragma unroll
                    for (int n = 0; n < 4; n++)
                        acc[mh * 4 + m2][n] = __builtin_amdgcn_mfma_f32_16x16x32_bf16(
                            af[m2], bfr[n][ks], acc[mh * 4 + m2][n], 0, 0, 0);
                __builtin_amdgcn_s_setprio(0);
            }
            if (st) {
                asm volatile("s_waitcnt vmcnt(0)" ::: "memory");
                __builtin_amdgcn_s_barrier();
            }
        }
    }
#undef STG

    const int cbase = qsel * 2048 + bn * 256;
#pragma unroll
    for (int m = 0; m < 8; m++) {
        const int row = bm * 256 + wr * 128 + m * 16 + lg * 4;
#pragma unroll
        for (int n = 0; n < 4; n++) {
            const int col = cbase + wc * 64 + n * 16 + lr;
#pragma unroll
            for (int h = 0; h < 2; h++) {
                const u32 tv = pk[m][n][h];
                const float o0 = bf2f((u16)(tv & 0xffff)) * sigm(acc[m][n][2 * h]);
                const float o1 = bf2f((u16)(tv >> 16)) * sigm(acc[m][n][2 * h + 1]);
                combo[(size_t)(row + 2 * h) * 8192 + col] = f2bf(o0);
                combo[(size_t)(row + 2 * h + 1) * 8192 + col] = f2bf(o1);
            }
        }
    }
}

// ================= unified NT GEMM: 128x256, BK=64, 1 barrier per K-tile =================
template <int EPI>
__global__ __launch_bounds__(512, 1)
void gemm_u(const u16* __restrict__ A, const u16* __restrict__ B,
            float* __restrict__ outF, u16* __restrict__ outB,
            const float* __restrict__ bias, const float* __restrict__ addend,
            const float* __restrict__ resid, float* __restrict__ outG,
            int M, int N, int K, int ldc) {
    extern __shared__ u16 lds[];   // 2 bufs x 24576 u16 = 98304 B
    const int nbn = N >> 8;
    const int nwg = (M >> 7) * nbn;
    const int orig = blockIdx.x;
    const int q8 = nwg >> 3, r8 = nwg & 7;
    const int xcd = orig & 7, lin = orig >> 3;
    const int wgid = (xcd < r8 ? xcd * (q8 + 1) : r8 * (q8 + 1) + (xcd - r8) * q8) + lin;
    const int g = wgid / (nbn << 3);
    const int rem = wgid - g * (nbn << 3);
    const int bn = rem >> 3;
    const int bm = (g << 3) + (rem & 7);

    const int t = threadIdx.x;
    const int w = t >> 6, l = t & 63;
    const int wr = w >> 2, wc = w & 3;
    const int lr = l & 15, lg = l >> 4;
    const int NT = K >> 6;

    const int pr = t >> 3, ps = t & 7;
    const int sg = ps ^ (pr & 7);
    const u16* aSrc = A + (size_t)(bm * 128 + pr) * K + sg * 8;
    const u16* bSrc = B + (size_t)(bn * 256 + pr) * K + sg * 8;
    const size_t rowStep = (size_t)64 * K;

#define STG_A(bi, ko) do { u16* da = lds + (bi) * 24576 + t * 8;                 \
        gl16(aSrc + (ko), da); gl16(aSrc + rowStep + (ko), da + 4096); } while (0)
#define STG_B01(bi, ko) do { u16* db = lds + (bi) * 24576 + 8192 + t * 8;        \
        gl16(bSrc + (ko), db); gl16(bSrc + rowStep + (ko), db + 4096); } while (0)
#define STG_B23(bi, ko) do { u16* db = lds + (bi) * 24576 + 8192 + t * 8;        \
        gl16(bSrc + 2 * rowStep + (ko), db + 8192);                              \
        gl16(bSrc + 3 * rowStep + (ko), db + 12288); } while (0)

    f32x4 acc[4][4];
#pragma unroll
    for (int i = 0; i < 4; i++)
#pragma unroll
        for (int j = 0; j < 4; j++) acc[i][j] = (f32x4){0.f, 0.f, 0.f, 0.f};

    const int xr = (lr & 7) << 4;
    const int kof[2] = { ((lg) << 4) ^ xr, ((4 + lg) << 4) ^ xr };

    STG_A(0, 0); STG_B01(0, 0); STG_B23(0, 0);
    asm volatile("s_waitcnt vmcnt(0)" ::: "memory");
    __builtin_amdgcn_s_barrier();

    for (int T = 0; T < NT; ++T) {
        const char* bufA = (const char*)lds + (size_t)(T & 1) * 49152;
        const char* bufB = bufA + 16384;
        const int sbi = (T + 1) & 1;
        const bool st = (T + 1) < NT;
        const size_t ko = (size_t)(T + 1) * 64;
        bf16x8 bf[4][2];
#pragma unroll
        for (int n = 0; n < 4; n++) {
            const int rb = wc * 64 + n * 16 + lr;
            bf[n][0] = *reinterpret_cast<const bf16x8*>(bufB + rb * 128 + kof[0]);
            bf[n][1] = *reinterpret_cast<const bf16x8*>(bufB + rb * 128 + kof[1]);
        }
#pragma unroll
        for (int p = 0; p < 4; ++p) {
            const int ks = p >> 1, mh = p & 1;
            bf16x8 af[2];
#pragma unroll
            for (int m2 = 0; m2 < 2; m2++) {
                const int ra = wr * 64 + (mh * 2 + m2) * 16 + lr;
                af[m2] = *reinterpret_cast<const bf16x8*>(bufA + ra * 128 + kof[ks]);
            }
            if (st) {
                if (p == 0) STG_A(sbi, ko);
                if (p == 1) STG_B01(sbi, ko);
                if (p == 2) STG_B23(sbi, ko);
            }
            __builtin_amdgcn_s_setprio(1);
#pragma unroll
            for (int m2 = 0; m2 < 2; m2++)
#pragma unroll
                for (int n = 0; n < 4; n++)
                    acc[mh * 2 + m2][n] = __builtin_amdgcn_mfma_f32_16x16x32_bf16(
                        af[m2], bf[n][ks], acc[mh * 2 + m2][n], 0, 0, 0);
            __builtin_amdgcn_s_setprio(0);
        }
        if (st) {
            asm volatile("s_waitcnt vmcnt(0)" ::: "memory");
            __builtin_amdgcn_s_barrier();
        }
    }
#undef STG_A
#undef STG_B01
#undef STG_B23

#pragma unroll
    for (int m = 0; m < 4; m++) {
        const int row = bm * 128 + wr * 64 + m * 16 + lg * 4;
#pragma unroll
        for (int n = 0; n < 4; n++) {
            const int col = bn * 256 + wc * 64 + n * 16 + lr;
#pragma unroll
            for (int q = 0; q < 4; q++) {
                const size_t idx = (size_t)(row + q) * ldc + col;
                const float v = acc[m][n][q];
                if (EPI == 0) {
                    outB[idx] = f2bf(v);
                } else if (EPI == 1) {
                    outF[idx] = v;
                    outB[idx] = f2bf(v);
                } else {
                    const float g2 = sigm(v + bias[col]);
                    outG[idx] = g2 * addend[idx] + (1.f - g2) * resid[idx];
                }
            }
        }
    }
}

// ---------------- causal flash attention (QBLK=128, 8 waves, reg-staged dbuf) ----------------
#define VSWZ(dh) (((((dh) >> 3) ^ (dh)) & 7) << 4)
__global__ __launch_bounds__(512) void flash_attn(const u16* __restrict__ qkv,
                                                  u16* __restrict__ out) {
    __shared__ u16 klds[2][64 * 128];
    __shared__ u16 vlds[2][128 * 64];
    __shared__ u16 plds[8][16 * 64];
    const int t = threadIdx.x, w = t >> 6, l = t & 63;
    const int lr = l & 15, lg = l >> 4;
    const int b0 = blockIdx.x;
    const int xcd = b0 & 7, i0 = b0 >> 3;
    const int bh = ((i0 & 3) << 3) | xcd;
    const int p = i0 >> 2;
    const int b = bh >> 4, h = bh & 15;
    const size_t base = (size_t)b * 2048;
    const int sr0 = t >> 4;
    const int sc0 = (t & 15) << 3;

    uint4 kreg0, kreg1, vreg0, vreg1;

#define STAGE_LOAD(KT) do {                                                          \
        const size_t gg = (base + (size_t)(KT) * 64 + sr0) * 6144 + h * 128 + sc0;   \
        kreg0 = *reinterpret_cast<const uint4*>(&qkv[gg + 2048]);                    \
        vreg0 = *reinterpret_cast<const uint4*>(&qkv[gg + 4096]);                    \
        kreg1 = *reinterpret_cast<const uint4*>(&qkv[gg + 32 * 6144 + 2048]);        \
        vreg1 = *reinterpret_cast<const uint4*>(&qkv[gg + 32 * 6144 + 4096]);        \
    } while (0)

#define STAGE_WRITE(BUF) do {                                                                     \
        char* kb = (char*)&klds[BUF][0];                                                          \
        char* vb = (char*)&vlds[BUF][0];                                                          \
        *reinterpret_cast<uint4*>(kb + ((sr0 * 256 + sc0 * 2) ^ ((sr0 & 7) << 4))) = kreg0;       \
        *reinterpret_cast<uint4*>(kb + (((sr0 + 32) * 256 + sc0 * 2) ^ ((sr0 & 7) << 4))) = kreg1;\
        union { uint4 u; u16 s[8]; } vv;                                                          \
        vv.u = vreg0;                                                                             \
        _Pragma("unroll")                                                                         \
        for (int jj = 0; jj < 8; jj++) {                                                          \
            const int dh = sc0 + jj;                                                              \
            *reinterpret_cast<u16*>(vb + ((dh * 128 + sr0 * 2) ^ VSWZ(dh))) = vv.s[jj];           \
        }                                                                                         \
        vv.u = vreg1;                                                                             \
        _Pragma("unroll")                                                                         \
        for (int jj = 0; jj < 8; jj++) {                                                          \
            const int dh = sc0 + jj;                                                              \
            *reinterpret_cast<u16*>(vb + ((dh * 128 + (sr0 + 32) * 2) ^ VSWZ(dh))) = vv.s[jj];    \
        }                                                                                         \
    } while (0)

    for (int phase = 0; phase < 2; ++phase) {
        const int qt = phase ? (15 - p) : p;
        const int last = 2 * qt + 1;
        const int qrow = qt * 128 + w * 16 + lr;
        const int qr0 = qt * 128 + w * 16 + lg * 4;
        bf16x8 qf[4];
#pragma unroll
        for (int kk = 0; kk < 4; kk++)
            qf[kk] = *reinterpret_cast<const bf16x8*>(
                &qkv[(base + qrow) * 6144 + h * 128 + kk * 32 + lg * 8]);
        f32x4 o[8];
#pragma unroll
        for (int i = 0; i < 8; i++) o[i] = (f32x4){0.f, 0.f, 0.f, 0.f};
        float m[4] = {-1e30f, -1e30f, -1e30f, -1e30f};
        float ls[4] = {0.f, 0.f, 0.f, 0.f};

        STAGE_LOAD(0);
        int cur = 0;
        STAGE_WRITE(0);
        __syncthreads();

        for (int kt = 0; kt <= last; ++kt) {
            if (kt < last) STAGE_LOAD(kt + 1);
            const char* kb = (const char*)&klds[cur][0];
            const char* vb = (const char*)&vlds[cur][0];
            f32x4 s[4];
#pragma unroll
            for (int nf = 0; nf < 4; nf++) {
                f32x4 a = (f32x4){0.f, 0.f, 0.f, 0.f};
                const int kv = nf * 16 + lr;
#pragma unroll
                for (int kk = 0; kk < 4; kk++) {
                    bf16x8 kf = *reinterpret_cast<const bf16x8*>(
                        kb + ((kv * 256 + kk * 64 + lg * 16) ^ ((kv & 7) << 4)));
                    a = __builtin_amdgcn_mfma_f32_16x16x32_bf16(qf[kk], kf, a, 0, 0, 0);
                }
                s[nf] = a;
            }
            if (kt >= 2 * qt) {
#pragma unroll
                for (int nf = 0; nf < 4; nf++) {
                    const int kvi = kt * 64 + nf * 16 + lr;
#pragma unroll
                    for (int q = 0; q < 4; q++)
                        if (kvi > qr0 + q) s[nf][q] = -1e30f;
                }
            }
            float mx[4] = {-1e30f, -1e30f, -1e30f, -1e30f};
#pragma unroll
            for (int nf = 0; nf < 4; nf++)
#pragma unroll
                for (int q = 0; q < 4; q++) mx[q] = fmaxf(mx[q], s[nf][q]);
#pragma unroll
            for (int q = 0; q < 4; q++) {
#pragma unroll
                for (int d = 1; d < 16; d <<= 1) mx[q] = fmaxf(mx[q], __shfl_xor(mx[q], d));
            }
            float fac[4], rs[4];
#pragma unroll
            for (int q = 0; q < 4; q++) {
                const float mn = fmaxf(m[q], mx[q]);
                fac[q] = __expf(m[q] - mn);
                m[q] = mn;
                rs[q] = 0.f;
            }
#pragma unroll
            for (int nf = 0; nf < 4; nf++) {
#pragma unroll
                for (int q = 0; q < 4; q++) {
                    const float pv = __expf(s[nf][q] - m[q]);
                    s[nf][q] = pv;
                    rs[q] += pv;
                }
            }
#pragma unroll
            for (int nf = 0; nf < 4; nf++) {
                const int col = nf * 16 + lr;
#pragma unroll
                for (int q = 0; q < 4; q++) {
                    const int row = lg * 4 + q;
                    *reinterpret_cast<u16*>((char*)&plds[w][0] +
                        ((row * 128 + col * 2) ^ ((row & 7) << 4))) = f2bf(s[nf][q]);
                }
            }
#pragma unroll
            for (int q = 0; q < 4; q++) {
#pragma unroll
                for (int d = 1; d < 16; d <<= 1) rs[q] += __shfl_xor(rs[q], d);
                ls[q] = ls[q] * fac[q] + rs[q];
            }
#pragma unroll
            for (int nf2 = 0; nf2 < 8; nf2++)
#pragma unroll
                for (int q = 0; q < 4; q++) o[nf2][q] *= fac[q];
#pragma unroll
            for (int ks = 0; ks < 2; ks++) {
                bf16x8 pf = *reinterpret_cast<const bf16x8*>((char*)&plds[w][0] +
                    ((lr * 128 + ks * 64 + lg * 16) ^ ((lr & 7) << 4)));
#pragma unroll
                for (int nf2 = 0; nf2 < 8; nf2++) {
                    const int dh = nf2 * 16 + lr;
                    bf16x8 vf = *reinterpret_cast<const bf16x8*>(
                        vb + ((dh * 128 + ks * 64 + lg * 16) ^ VSWZ(dh)));
                    o[nf2] = __builtin_amdgcn_mfma_f32_16x16x32_bf16(pf, vf, o[nf2], 0, 0, 0);
                }
            }
            if (kt < last) STAGE_WRITE(cur ^ 1);
            __syncthreads();
            cur ^= 1;
        }
#pragma unroll
        for (int nf2 = 0; nf2 < 8; nf2++) {
            const int col = h * 128 + nf2 * 16 + lr;
#pragma unroll
            for (int q = 0; q < 4; q++) {
                const float v = o[nf2][q] / ls[q];
                out[(base + qr0 + q) * 2048 + col] = f2bf(v);
            }
        }
        __syncthreads();
    }
#undef STAGE_LOAD
#undef STAGE_WRITE
}

// ---------------- launch ----------------
extern "C" void kernel_launch(void* const* d_in, const int* in_sizes, int n_in,
                              void* d_out, int out_size, void* d_ws, size_t ws_size,
                              hipStream_t stream) {
    const float* x      = (const float*)d_in[0];
    const float* q_w    = (const float*)d_in[1];
    const float* k_w    = (const float*)d_in[2];
    const float* v_w    = (const float*)d_in[3];
    const float* o_w    = (const float*)d_in[4];
    const float* temp   = (const float*)d_in[5];
    const float* ln1_w  = (const float*)d_in[6];
    const float* ln2_w  = (const float*)d_in[7];
    const float* gate_w = (const float*)d_in[8];
    const float* up_w   = (const float*)d_in[9];
    const float* gate2_w= (const float*)d_in[10];
    const float* down_w = (const float*)d_in[11];
    const float* ag_w   = (const float*)d_in[12];
    const float* ag_b   = (const float*)d_in[13];
    const float* fg_w   = (const float*)d_in[14];
    const float* fg_b   = (const float*)d_in[15];

    const int GEMM_LDS = 98304;
    const int SW_LDS   = 131072;
    (void)hipFuncSetAttribute(reinterpret_cast<const void*>(&gemm_u<0>),
                              hipFuncAttributeMaxDynamicSharedMemorySize, GEMM_LDS);
    (void)hipFuncSetAttribute(reinterpret_cast<const void*>(&gemm_u<1>),
                              hipFuncAttributeMaxDynamicSharedMemorySize, GEMM_LDS);
    (void)hipFuncSetAttribute(reinterpret_cast<const void*>(&gemm_u<2>),
                              hipFuncAttributeMaxDynamicSharedMemorySize, GEMM_LDS);
    (void)hipFuncSetAttribute(reinterpret_cast<const void*>(&gemm_swiglu),
                              hipFuncAttributeMaxDynamicSharedMemorySize, SW_LDS);

    // ---- workspace regions (peak 251,658,240 B; lifetimes disjoint) ----
    char* ws = (char*)d_ws;
    u16*  Wbuf = (u16*)(ws);                      // 33,554,432 B = 4 DD slots
    u16*  hbuf = (u16*)(ws + 33554432);           // 16,777,216 B
    float* x1  = (float*)(ws + 50331648);         // 33,554,432 B
    u16*  combo= (u16*)(ws + 83886080);           // 67,108,864 B
    char* E    = ws + 150994944;                  // 50,331,648 B
    char* F    = ws + 201326592;                  // 33,554,432 B
    u16*  ffb  = (u16*)(ws + 234881024);          // 16,777,216 B

    u16*   qkvact = (u16*)E;
    float* aof    = (float*)E;
    u16*   aob    = (u16*)(E + 33554432);
    u16*   Wffn2  = (u16*)E;
    u16*   Wdn    = (u16*)E;
    u16*   attnb  = (u16*)F;
    float* fff    = (float*)F;

    float* outp = (float*)d_out;
    const size_t DD = 2048ull * 2048ull;
    const int cg_d = (int)(DD / 4) / 256;
    const int GRID_BIG = 32 * 24;
    const int GRID_SM  = 32 * 8;

    // 1) h = rmsnorm(x, ln1)
    hipLaunchKernelGGL(rmsnorm_k, dim3(4096), dim3(256), 0, stream, x, ln1_w, hbuf);

    // 2) qkv = h @ [Wq;Wk;Wv]^T
    hipLaunchKernelGGL(conv3_bf16, dim3(cg_d, 3), dim3(256), 0, stream,
                       q_w, k_w, v_w, Wbuf, Wbuf + DD, Wbuf + 2 * DD, (int)(DD / 4));
    hipLaunchKernelGGL((gemm_u<0>), dim3(GRID_BIG), dim3(512), GEMM_LDS, stream,
                       hbuf, Wbuf, (float*)nullptr, qkvact,
                       (const float*)nullptr, (const float*)nullptr, (const float*)nullptr,
                       (float*)nullptr, 4096, 6144, 2048, 6144);

    // convert o/ag/fg weights (fg parked at slot 3)
    hipLaunchKernelGGL(conv3_bf16, dim3(cg_d, 3), dim3(256), 0, stream,
                       o_w, ag_w, fg_w, Wbuf, Wbuf + DD, Wbuf + 3 * DD, (int)(DD / 4));

    // 3) l2-normalize q,k (q scaled by temp)
    hipLaunchKernelGGL(qk_l2norm, dim3(32768), dim3(256), 0, stream, qkvact, temp);

    // 4) attention
    hipLaunchKernelGGL(flash_attn, dim3(256), dim3(512), 0, stream, qkvact, attnb);

    // 5) attn_out = attn @ Wo^T
    hipLaunchKernelGGL((gemm_u<1>), dim3(GRID_SM), dim3(512), GEMM_LDS, stream,
                       attnb, Wbuf, aof, aob,
                       (const float*)nullptr, (const float*)nullptr, (const float*)nullptr,
                       (float*)nullptr, 4096, 2048, 2048, 2048);

    // 6) x1 = sigmoid(attn_out@Wag^T + b)*attn_out + (1-g)*x
    hipLaunchKernelGGL((gemm_u<2>), dim3(GRID_SM), dim3(512), GEMM_LDS, stream,
                       aob, Wbuf + DD, (float*)nullptr, (u16*)nullptr,
                       ag_b, aof, x, x1, 4096, 2048, 2048, 2048);

    // 7) h2 = rmsnorm(x1, ln2)
    hipLaunchKernelGGL(rmsnorm_k, dim3(4096), dim3(256), 0, stream, x1, ln2_w, hbuf);

    // 8) FFN: 2 half-dispatches; both quarters' weights converted in ONE conv6 launch
    for (int d = 0; d < 2; d++) {
        const size_t w0 = (size_t)(2 * d) * 2048 * 2048;
        const size_t w1 = (size_t)(2 * d + 1) * 2048 * 2048;
        hipLaunchKernelGGL(conv6_bf16, dim3(cg_d, 6), dim3(256), 0, stream,
                           gate_w, up_w, gate2_w, Wbuf, Wffn2, w0, w1, (int)(DD / 4));
        hipLaunchKernelGGL(gemm_swiglu, dim3(256), dim3(512), SW_LDS, stream,
                           hbuf, Wbuf, Wffn2, combo + (size_t)d * 2 * 2048, 2048);
    }

    // 9) ffn_out = combo @ Wdn^T
    hipLaunchKernelGGL(conv_bf16, dim3(16384), dim3(256), 0, stream, down_w, Wdn, (int)(2048ull * 8192 / 4));
    hipLaunchKernelGGL((gemm_u<1>), dim3(GRID_SM), dim3(512), GEMM_LDS, stream,
                       combo, Wdn, fff, ffb,
                       (const float*)nullptr, (const float*)nullptr, (const float*)nullptr,
                       (float*)nullptr, 4096, 2048, 8192, 2048);

    // 10) out = sigmoid(ffn_out@Wfg^T + b)*ffn_out + (1-g)*x1
    hipLaunchKernelGGL((gemm_u<2>), dim3(GRID_SM), dim3(512), GEMM_LDS, stream,
                       ffb, Wbuf + 3 * DD, (float*)nullptr, (u16*)nullptr,
                       fg_b, fff, x1, outp, 4096, 2048, 2048, 2048);
}